// Round 9
// baseline (570.503 us; speedup 1.0000x reference)
//
#include <hip/hip_runtime.h>

typedef unsigned short u16;
typedef unsigned int u32;
typedef __bf16 bf16x8 __attribute__((ext_vector_type(8)));
typedef float f32x4 __attribute__((ext_vector_type(4)));

#define MFMA_BF16(a, b, c) __builtin_amdgcn_mfma_f32_16x16x32_bf16(a, b, c, 0, 0, 0)

#define NBUC_MAX 512
#define BCAP 4608
#define EPB 8192  // edges per block in bucket_scatter

__device__ __forceinline__ float bf2f(u16 h) {
  u32 u = ((u32)h) << 16;
  return __builtin_bit_cast(float, u);
}
__device__ __forceinline__ u16 f2bf(float f) {
  u32 u = __builtin_bit_cast(u32, f);
  u += 0x7fffu + ((u >> 16) & 1u);
  return (u16)(u >> 16);
}

// ---- weight prep: 6 conv weights fp32 [k][n] -> bf16 transposed [n][k], one dispatch
__global__ __launch_bounds__(256) void prep_w6(const float* __restrict__ w0,
                                               const float* __restrict__ w1,
                                               const float* __restrict__ w2,
                                               const float* __restrict__ w3,
                                               const float* __restrict__ w4,
                                               const float* __restrict__ w5,
                                               u16* __restrict__ wt) {
  const int which = blockIdx.x >> 6;
  const float* w = which == 0 ? w0 : which == 1 ? w1 : which == 2 ? w2
                  : which == 3 ? w3 : which == 4 ? w4 : w5;
  int t = (blockIdx.x & 63) * 256 + threadIdx.x;  // 16384 elems per matrix
  int n = t >> 7, k = t & 127;
  wt[which * 16384 + n * 128 + k] = f2bf(w[k * 128 + n]);
}

// ---- initial MLP applied to the 500-row embedding table (h0 = table2[x])
__global__ __launch_bounds__(128) void mlp0_table(
    const float* __restrict__ emb, const float* __restrict__ w1, const float* __restrict__ b1,
    const float* __restrict__ w2, const float* __restrict__ b2, u16* __restrict__ table) {
  __shared__ float e[128];
  __shared__ float tt[128];
  int r = blockIdx.x, j = threadIdx.x;
  e[j] = emb[r * 128 + j];
  __syncthreads();
  float s = b1[j];
  for (int k = 0; k < 128; ++k) s += e[k] * w1[k * 128 + j];
  tt[j] = s > 0.f ? s : 0.f;
  __syncthreads();
  float s2 = b2[j];
  for (int k = 0; k < 128; ++k) s2 += tt[k] * w2[k * 128 + j];
  table[r * 128 + j] = f2bf(s2);
}

// ---- pass 1: bucket edges by dst>>8, packed (src<<8)|dloc. No LDS staging (round 8's
// 48 KB sv/sb capped occupancy at ~3 blocks/CU on a latency-bound kernel); re-read
// src/dst from L2 in the scatter pass instead. LDS = 4 KB.
__global__ __launch_bounds__(256) void bucket_scatter(const int* __restrict__ src,
                                                      const int* __restrict__ dst,
                                                      u32* __restrict__ pairs,
                                                      u32* __restrict__ cursor, int E_, int nbuc) {
  __shared__ u32 lcnt[NBUC_MAX];
  __shared__ u32 lbase[NBUC_MAX];
  const int t = threadIdx.x;
  for (int b = t; b < NBUC_MAX; b += 256) lcnt[b] = 0;
  __syncthreads();
  const int e0 = blockIdx.x * EPB;
#pragma unroll
  for (int it = 0; it < EPB / 256; ++it) {
    int e = e0 + it * 256 + t;
    if (e < E_) atomicAdd(&lcnt[((u32)dst[e]) >> 8], 1u);
  }
  __syncthreads();
  for (int b = t; b < nbuc; b += 256) {
    u32 c = lcnt[b];
    lbase[b] = c ? atomicAdd(&cursor[b], c) : 0u;
    lcnt[b] = 0;
  }
  __syncthreads();
#pragma unroll
  for (int it = 0; it < EPB / 256; ++it) {
    int e = e0 + it * 256 + t;
    if (e < E_) {
      int d = dst[e];
      u32 b = ((u32)d) >> 8;
      u32 r = atomicAdd(&lcnt[b], 1u);
      u32 p = lbase[b] + r;
      if (p < BCAP) pairs[(size_t)b * BCAP + p] = (((u32)src[e]) << 8) | (u32)(d & 255);
    }
  }
}

// ---- pass 2: per-bucket exact CSR (256 nodes/bucket): LDS count + scan + rank scatter
__global__ __launch_bounds__(256) void csr_build(const u32* __restrict__ pairs,
                                                 const u32* __restrict__ cursor,
                                                 u32* __restrict__ csr, int* __restrict__ RS,
                                                 int* __restrict__ DEG, int nrows) {
  __shared__ u32 cnt[256];
  __shared__ u32 offs[256];
  __shared__ u32 basearr[256];
  const int b = blockIdx.x, t = threadIdx.x;
  u32 count = cursor[b];
  if (count > BCAP) count = BCAP;
  cnt[t] = 0;
  __syncthreads();
  const u32* pb = pairs + (size_t)b * BCAP;
  for (u32 i = t; i < count; i += 256) atomicAdd(&cnt[pb[i] & 255u], 1u);
  __syncthreads();
  const u32 my = cnt[t];
  offs[t] = my;
  __syncthreads();
  for (int d = 1; d < 256; d <<= 1) {
    u32 v = (t >= d) ? offs[t - d] : 0u;
    __syncthreads();
    offs[t] += v;
    __syncthreads();
  }
  const u32 excl = offs[t] - my;  // exclusive prefix
  const int node = (b << 8) + t;
  if (node < nrows) {
    RS[node] = b * BCAP + (int)excl;
    DEG[node] = (int)my;
  }
  basearr[t] = excl;
  cnt[t] = 0;
  __syncthreads();
  for (u32 i = t; i < count; i += 256) {
    u32 v = pb[i];
    u32 dl = v & 255u;
    u32 r = atomicAdd(&cnt[dl], 1u);
    csr[(size_t)b * BCAP + basearr[dl] + r] = v >> 8;
  }
}

// ---- aggregation: AGG[i] = row(i) + sum_j row(j), PURE gather+add.
// BN+relu is applied once per NODE by bn_apply beforehand (E/N = 16x less VALU than
// the round-3..8 per-edge fusion; agg was VALU-bound at 65% busy).
// MODE 0: row(i) = TBL[x[i]] (layer 0).  MODE 1: row(i) = H[i] (already BN+relu'd).
template <int MODE>
__global__ __launch_bounds__(256) void agg_kernel(
    const u16* __restrict__ Hsrc, const int* __restrict__ x, const u32* __restrict__ csr,
    const int* __restrict__ RS, const int* __restrict__ DEG, u16* __restrict__ AGG, int nrows) {
  int node = blockIdx.x * 4 + (threadIdx.x >> 6);
  if (node >= nrows) return;
  const int lane = threadIdx.x & 63;
  const int grp = lane >> 4;  // neighbor sub-slot 0..3
  const int fl = lane & 15;   // 16B feature chunk
  const int deg = DEG[node];
  const u32* cl = csr + RS[node];
  const char* Hb = (const char*)Hsrc;
  const u32 flo = (u32)fl << 4;

  float a[8];
#pragma unroll
  for (int i = 0; i < 8; ++i) a[i] = 0.f;

#define ACCUM(vv)                                   \
  {                                                 \
    const u16* p = (const u16*)&(vv);               \
    _Pragma("unroll") for (int i = 0; i < 8; ++i) a[i] += bf2f(p[i]); \
  }
#define ROWOFF(idx) ((((u32)(MODE == 0 ? x[(idx)] : (idx))) << 8) + flo)

  if (grp == 0) {
    uint4 v = *(const uint4*)(Hb + ROWOFF(node));
    ACCUM(v);
  }
  int j = grp;
  int cA = (j < deg) ? (int)cl[j] : 0;
  int cB = (j + 4 < deg) ? (int)cl[j + 4] : 0;
  uint4 nv = make_uint4(0u, 0u, 0u, 0u);
  if (j < deg) nv = *(const uint4*)(Hb + ROWOFF(cA));
  while (j < deg) {
    uint4 cv = nv;
    int cn = cB;
    cB = (j + 8 < deg) ? (int)cl[j + 8] : 0;
    if (j + 4 < deg) nv = *(const uint4*)(Hb + ROWOFF(cn));
    ACCUM(cv);
    j += 4;
  }
#undef ROWOFF
#undef ACCUM

#pragma unroll
  for (int i = 0; i < 8; ++i) {
    a[i] += __shfl_xor(a[i], 16);
    a[i] += __shfl_xor(a[i], 32);
  }
  if (grp == 0) {
    u32 o[4];
#pragma unroll
    for (int i = 0; i < 4; ++i) o[i] = (u32)f2bf(a[2 * i]) | ((u32)f2bf(a[2 * i + 1]) << 16);
    *(uint4*)(AGG + (size_t)node * 128 + fl * 8) = *(uint4*)o;
  }
}

// ---- BN apply + relu, in place on H (elementwise per row -> race-free; round-2 proven)
__global__ __launch_bounds__(256) void bn_apply(u16* __restrict__ Hh,
                                                const float* __restrict__ scsh, int total16) {
  int t = blockIdx.x * 256 + threadIdx.x;
  if (t >= total16) return;
  int seg = t & 15;
  uint4 v = *(uint4*)(Hh + (size_t)t * 8);
  u16* p = (u16*)&v;
  u16 o[8];
#pragma unroll
  for (int i = 0; i < 8; ++i) {
    int f = seg * 8 + i;
    float xv = bf2f(p[i]) * scsh[f] + scsh[128 + f];
    xv = xv > 0.f ? xv : 0.f;
    o[i] = f2bf(xv);
  }
  *(uint4*)(Hh + (size_t)t * 8) = *(uint4*)o;
}

// ---- fused 2-layer MLP (bf16 MFMA), 64-row x 128-col tile per block, 4 waves
// Y = relu(X@W1+b1)@W2+b2 ; per-column sum/sumsq via same-address global atomics
// (proven cheap in r6; the "contention-free" PART+1-block-reduce cost 318 us in r7).
__global__ __launch_bounds__(256) void mlp_kernel(
    const u16* __restrict__ X, const u16* __restrict__ W1t, const float* __restrict__ b1,
    const u16* __restrict__ W2t, const float* __restrict__ b2, u16* __restrict__ Y,
    float* __restrict__ stats, int nrows) {
  __shared__ u16 Xs[64 * 136];
  __shared__ u16 Ts[64 * 136];
  const int t = threadIdx.x;
  const int row0 = blockIdx.x * 64;
  {
    const int seg = t & 15;
    const int rb = t >> 4;
#pragma unroll
    for (int p = 0; p < 4; ++p) {
      const int r = rb + p * 16;
      const int gr = row0 + r;
      uint4 v = make_uint4(0u, 0u, 0u, 0u);
      if (gr < nrows) v = *(const uint4*)(X + (size_t)gr * 128 + seg * 8);
      *(uint4*)(Xs + r * 136 + seg * 8) = v;
    }
  }
  __syncthreads();
  const int lane = t & 63;
  const int wave = t >> 6;
  const int n0 = wave * 32;
  const int nl = lane & 15;
  const int quad = lane >> 4;

  bf16x8 bw[2][4];
#pragma unroll
  for (int nt = 0; nt < 2; ++nt)
#pragma unroll
    for (int kk = 0; kk < 4; ++kk)
      bw[nt][kk] = *(const bf16x8*)(W1t + (size_t)(n0 + nt * 16 + nl) * 128 + kk * 32 + quad * 8);

  f32x4 acc[4][2];
#pragma unroll
  for (int mt = 0; mt < 4; ++mt) {
    acc[mt][0] = (f32x4)0.0f;
    acc[mt][1] = (f32x4)0.0f;
  }
#pragma unroll
  for (int kk = 0; kk < 4; ++kk) {
#pragma unroll
    for (int mt = 0; mt < 4; ++mt) {
      bf16x8 a = *(const bf16x8*)(Xs + (mt * 16 + nl) * 136 + kk * 32 + quad * 8);
      acc[mt][0] = MFMA_BF16(a, bw[0][kk], acc[mt][0]);
      acc[mt][1] = MFMA_BF16(a, bw[1][kk], acc[mt][1]);
    }
  }
  // epilogue 1: bias + relu -> Ts (bf16)
#pragma unroll
  for (int nt = 0; nt < 2; ++nt) {
    const int n = n0 + nt * 16 + nl;
    const float bias = b1[n];
#pragma unroll
    for (int mt = 0; mt < 4; ++mt)
#pragma unroll
      for (int r = 0; r < 4; ++r) {
        float v = acc[mt][nt][r] + bias;
        v = v > 0.f ? v : 0.f;
        Ts[(mt * 16 + quad * 4 + r) * 136 + n] = f2bf(v);
      }
  }
  __syncthreads();
  // GEMM2
#pragma unroll
  for (int nt = 0; nt < 2; ++nt)
#pragma unroll
    for (int kk = 0; kk < 4; ++kk)
      bw[nt][kk] = *(const bf16x8*)(W2t + (size_t)(n0 + nt * 16 + nl) * 128 + kk * 32 + quad * 8);
#pragma unroll
  for (int mt = 0; mt < 4; ++mt) {
    acc[mt][0] = (f32x4)0.0f;
    acc[mt][1] = (f32x4)0.0f;
  }
#pragma unroll
  for (int kk = 0; kk < 4; ++kk) {
#pragma unroll
    for (int mt = 0; mt < 4; ++mt) {
      bf16x8 a = *(const bf16x8*)(Ts + (mt * 16 + nl) * 136 + kk * 32 + quad * 8);
      acc[mt][0] = MFMA_BF16(a, bw[0][kk], acc[mt][0]);
      acc[mt][1] = MFMA_BF16(a, bw[1][kk], acc[mt][1]);
    }
  }
  // epilogue 2: bias, store Y (bf16), BN stats
  float ssum[2] = {0.f, 0.f}, ssq[2] = {0.f, 0.f};
#pragma unroll
  for (int nt = 0; nt < 2; ++nt) {
    const int n = n0 + nt * 16 + nl;
    const float bias = b2[n];
#pragma unroll
    for (int mt = 0; mt < 4; ++mt)
#pragma unroll
      for (int r = 0; r < 4; ++r) {
        const int row = row0 + mt * 16 + quad * 4 + r;
        float v = acc[mt][nt][r] + bias;
        if (row < nrows) {
          Y[(size_t)row * 128 + n] = f2bf(v);
          ssum[nt] += v;
          ssq[nt] += v * v;
        }
      }
  }
#pragma unroll
  for (int nt = 0; nt < 2; ++nt) {
    float s = ssum[nt], q = ssq[nt];
    s += __shfl_xor(s, 16);
    q += __shfl_xor(q, 16);
    s += __shfl_xor(s, 32);
    q += __shfl_xor(q, 32);
    if (quad == 0) {
      const int n = n0 + nt * 16 + nl;
      atomicAdd(&stats[n], s);
      atomicAdd(&stats[128 + n], q);
    }
  }
}

// ---- BN finalize: per-feature scale/shift from sums (tiny; ~free)
__global__ __launch_bounds__(128) void bn_finalize(const float* __restrict__ stats,
                                                   const float* __restrict__ g,
                                                   const float* __restrict__ be,
                                                   float* __restrict__ scsh, float invN) {
  int f = threadIdx.x;
  float mu = stats[f] * invN;
  float var = stats[128 + f] * invN - mu * mu;
  float rstd = rsqrtf(var + 1e-5f);
  float sc = rstd * g[f];
  scsh[f] = sc;
  scsh[128 + f] = be[f] - mu * sc;
}

// ---- pooling (fused layer-3 BN+relu via precomputed scsh) + final head, one block/graph
__global__ __launch_bounds__(256) void pool_final(
    const u16* __restrict__ Hh, const int* __restrict__ batch, const float* __restrict__ scsh,
    const float* __restrict__ f1w, const float* __restrict__ f1b, const float* __restrict__ f2w,
    const float* __restrict__ f2b, float* __restrict__ out, int nrows) {
  __shared__ float red[16][128];
  __shared__ float pr[128];
  __shared__ float tt[128];
  const int gid = blockIdx.x, t = threadIdx.x;
  int l = 0, r = nrows;
  while (l < r) {
    int m = (l + r) >> 1;
    if (batch[m] < gid) l = m + 1; else r = m;
  }
  const int s0 = l;
  r = nrows;
  while (l < r) {
    int m = (l + r) >> 1;
    if (batch[m] < gid + 1) l = m + 1; else r = m;
  }
  const int s1 = l;
  const int fl = t & 15;
  const int grp = t >> 4;
  float sc[8], sh[8];
#pragma unroll
  for (int i = 0; i < 8; ++i) {
    sc[i] = scsh[fl * 8 + i];
    sh[i] = scsh[128 + fl * 8 + i];
  }
  float a[8];
#pragma unroll
  for (int i = 0; i < 8; ++i) a[i] = 0.f;
  for (int i = s0 + grp; i < s1; i += 16) {
    uint4 v = *(const uint4*)(Hh + (size_t)i * 128 + fl * 8);
    const u16* pp = (const u16*)&v;
#pragma unroll
    for (int k = 0; k < 8; ++k) {
      float xv = bf2f(pp[k]) * sc[k] + sh[k];
      a[k] += xv > 0.f ? xv : 0.f;
    }
  }
#pragma unroll
  for (int k = 0; k < 8; ++k) red[grp][fl * 8 + k] = a[k];
  __syncthreads();
  if (t < 128) {
    float s = 0.f;
#pragma unroll
    for (int gg2 = 0; gg2 < 16; ++gg2) s += red[gg2][t];
    pr[t] = s;
  }
  __syncthreads();
  if (t < 128) {
    float s = f1b[t];
    for (int k = 0; k < 128; ++k) s += pr[k] * f1w[k * 128 + t];
    tt[t] = s > 0.f ? s : 0.f;
  }
  __syncthreads();
  if (t < 10) {
    float s2 = f2b[t];
    for (int k = 0; k < 128; ++k) s2 += tt[k] * f2w[k * 10 + t];
    out[gid * 10 + t] = s2;
  }
}

// ws layout (bytes):
//   H     @ 0          : 25,600,000  (bf16 node features)
//   AGG   @ 25,600,000 : 25,600,000  (bf16 aggregated, layer input tiles)
//   PAIRS @ 51,200,000 : 512*4608*4 = 9,437,184
//   CSR   @ 60,637,184 : 9,437,184
//   RS    @ 70,074,368 : 400,000
//   DEG   @ 70,474,368 : 400,000
//   CUR   @ 70,874,368 : 2,048       (zeroed)
//   STATS @ 70,876,416 : 3,072       (3 layers x 256 f32; zeroed, contiguous w/ CUR)
//   SCSH  @ 70,879,488 : 3,072       (3 layers x 256 f32; written by bn_finalize)
//   WT    @ 70,882,560 : 196,608
//   TBL   @ 71,079,168 : 128,000
extern "C" void kernel_launch(void* const* d_in, const int* in_sizes, int n_in, void* d_out,
                              int out_size, void* d_ws, size_t ws_size, hipStream_t stream) {
  const int* x = (const int*)d_in[0];
  const int* ei = (const int*)d_in[1];
  const int* batch = (const int*)d_in[2];
  const float* emb = (const float*)d_in[3];
  const float* iw1 = (const float*)d_in[4];
  const float* ib1 = (const float*)d_in[5];
  const float* iw2 = (const float*)d_in[6];
  const float* ib2 = (const float*)d_in[7];
  const float* f1w = (const float*)d_in[8];
  const float* f1b = (const float*)d_in[9];
  const float* f2w = (const float*)d_in[10];
  const float* f2b = (const float*)d_in[11];
  const float* cw1[3] = {(const float*)d_in[12], (const float*)d_in[18], (const float*)d_in[24]};
  const float* cb1[3] = {(const float*)d_in[13], (const float*)d_in[19], (const float*)d_in[25]};
  const float* cw2[3] = {(const float*)d_in[14], (const float*)d_in[20], (const float*)d_in[26]};
  const float* cb2[3] = {(const float*)d_in[15], (const float*)d_in[21], (const float*)d_in[27]};
  const float* gg[3] = {(const float*)d_in[16], (const float*)d_in[22], (const float*)d_in[28]};
  const float* bb[3] = {(const float*)d_in[17], (const float*)d_in[23], (const float*)d_in[29]};

  const int N_ = in_sizes[0];
  const int E_ = in_sizes[1] / 2;
  const int V_ = in_sizes[3] / 128;
  const int G_ = out_size / 10;
  const int NBUC = (N_ + 255) >> 8;
  const float invN = 1.0f / (float)N_;

  char* ws = (char*)d_ws;
  u16* H = (u16*)(ws + 0);
  u16* AGG = (u16*)(ws + 25600000);
  u32* PAIRS = (u32*)(ws + 51200000);
  u32* CSR = (u32*)(ws + 60637184);
  int* RS = (int*)(ws + 70074368);
  int* DEG = (int*)(ws + 70474368);
  u32* CUR = (u32*)(ws + 70874368);
  float* STATS = (float*)(ws + 70876416);
  float* SCSH = (float*)(ws + 70879488);
  u16* WT = (u16*)(ws + 70882560);
  u16* TBL = (u16*)(ws + 71079168);

  hipMemsetAsync(ws + 70874368, 0, 5120, stream);  // CUR + STATS

  prep_w6<<<384, 256, 0, stream>>>(cw1[0], cw2[0], cw1[1], cw2[1], cw1[2], cw2[2], WT);
  mlp0_table<<<V_, 128, 0, stream>>>(emb, iw1, ib1, iw2, ib2, TBL);
  bucket_scatter<<<(E_ + EPB - 1) / EPB, 256, 0, stream>>>(ei, ei + E_, PAIRS, CUR, E_, NBUC);
  csr_build<<<NBUC, 256, 0, stream>>>(PAIRS, CUR, CSR, RS, DEG, N_);

  const int ablk = (N_ + 3) / 4;
  const int mblk = (N_ + 63) / 64;
  for (int l = 0; l < 3; ++l) {
    const u16* W1 = WT + (size_t)l * 32768;
    const u16* W2 = WT + (size_t)l * 32768 + 16384;
    if (l == 0) {
      agg_kernel<0><<<ablk, 256, 0, stream>>>(TBL, x, CSR, RS, DEG, AGG, N_);
    } else {
      bn_apply<<<(N_ * 16 + 255) / 256, 256, 0, stream>>>(H, SCSH + (l - 1) * 256, N_ * 16);
      agg_kernel<1><<<ablk, 256, 0, stream>>>(H, nullptr, CSR, RS, DEG, AGG, N_);
    }
    mlp_kernel<<<mblk, 256, 0, stream>>>(AGG, W1, cb1[l], W2, cb2[l], H, STATS + l * 256, N_);
    bn_finalize<<<1, 128, 0, stream>>>(STATS + l * 256, gg[l], bb[l], SCSH + l * 256, invN);
  }
  pool_final<<<G_, 256, 0, stream>>>(H, batch, SCSH + 2 * 256, f1w, f1b, f2w, f2b,
                                     (float*)d_out, N_);
}

// Round 10
// 556.410 us; speedup vs baseline: 1.0253x; 1.0253x over previous
//
#include <hip/hip_runtime.h>

typedef unsigned short u16;
typedef unsigned int u32;
typedef __bf16 bf16x8 __attribute__((ext_vector_type(8)));
typedef float f32x4 __attribute__((ext_vector_type(4)));
typedef float f32x2 __attribute__((ext_vector_type(2)));

#define MFMA_BF16(a, b, c) __builtin_amdgcn_mfma_f32_16x16x32_bf16(a, b, c, 0, 0, 0)

#define NBUC_MAX 512
#define BCAP 4608
#define EPB 8192  // edges per block in bucket_scatter

__device__ __forceinline__ float bf2f(u16 h) {
  u32 u = ((u32)h) << 16;
  return __builtin_bit_cast(float, u);
}
__device__ __forceinline__ u16 f2bf(float f) {
  u32 u = __builtin_bit_cast(u32, f);
  u += 0x7fffu + ((u >> 16) & 1u);
  return (u16)(u >> 16);
}

// ---- weight prep: 6 conv weights fp32 [k][n] -> bf16 transposed [n][k], one dispatch
__global__ __launch_bounds__(256) void prep_w6(const float* __restrict__ w0,
                                               const float* __restrict__ w1,
                                               const float* __restrict__ w2,
                                               const float* __restrict__ w3,
                                               const float* __restrict__ w4,
                                               const float* __restrict__ w5,
                                               u16* __restrict__ wt) {
  const int which = blockIdx.x >> 6;
  const float* w = which == 0 ? w0 : which == 1 ? w1 : which == 2 ? w2
                  : which == 3 ? w3 : which == 4 ? w4 : w5;
  int t = (blockIdx.x & 63) * 256 + threadIdx.x;  // 16384 elems per matrix
  int n = t >> 7, k = t & 127;
  wt[which * 16384 + n * 128 + k] = f2bf(w[k * 128 + n]);
}

// ---- initial MLP applied to the 500-row embedding table (h0 = table2[x])
__global__ __launch_bounds__(128) void mlp0_table(
    const float* __restrict__ emb, const float* __restrict__ w1, const float* __restrict__ b1,
    const float* __restrict__ w2, const float* __restrict__ b2, u16* __restrict__ table) {
  __shared__ float e[128];
  __shared__ float tt[128];
  int r = blockIdx.x, j = threadIdx.x;
  e[j] = emb[r * 128 + j];
  __syncthreads();
  float s = b1[j];
  for (int k = 0; k < 128; ++k) s += e[k] * w1[k * 128 + j];
  tt[j] = s > 0.f ? s : 0.f;
  __syncthreads();
  float s2 = b2[j];
  for (int k = 0; k < 128; ++k) s2 += tt[k] * w2[k * 128 + j];
  table[r * 128 + j] = f2bf(s2);
}

// ---- pass 1: bucket edges by dst>>8, packed (src<<8)|dloc. No LDS staging; LDS = 4 KB.
__global__ __launch_bounds__(256) void bucket_scatter(const int* __restrict__ src,
                                                      const int* __restrict__ dst,
                                                      u32* __restrict__ pairs,
                                                      u32* __restrict__ cursor, int E_, int nbuc) {
  __shared__ u32 lcnt[NBUC_MAX];
  __shared__ u32 lbase[NBUC_MAX];
  const int t = threadIdx.x;
  for (int b = t; b < NBUC_MAX; b += 256) lcnt[b] = 0;
  __syncthreads();
  const int e0 = blockIdx.x * EPB;
#pragma unroll
  for (int it = 0; it < EPB / 256; ++it) {
    int e = e0 + it * 256 + t;
    if (e < E_) atomicAdd(&lcnt[((u32)dst[e]) >> 8], 1u);
  }
  __syncthreads();
  for (int b = t; b < nbuc; b += 256) {
    u32 c = lcnt[b];
    lbase[b] = c ? atomicAdd(&cursor[b], c) : 0u;
    lcnt[b] = 0;
  }
  __syncthreads();
#pragma unroll
  for (int it = 0; it < EPB / 256; ++it) {
    int e = e0 + it * 256 + t;
    if (e < E_) {
      int d = dst[e];
      u32 b = ((u32)d) >> 8;
      u32 r = atomicAdd(&lcnt[b], 1u);
      u32 p = lbase[b] + r;
      if (p < BCAP) pairs[(size_t)b * BCAP + p] = (((u32)src[e]) << 8) | (u32)(d & 255);
    }
  }
}

// ---- pass 2: per-bucket exact CSR (256 nodes/bucket): LDS count + scan + rank scatter
__global__ __launch_bounds__(256) void csr_build(const u32* __restrict__ pairs,
                                                 const u32* __restrict__ cursor,
                                                 u32* __restrict__ csr, int* __restrict__ RS,
                                                 int* __restrict__ DEG, int nrows) {
  __shared__ u32 cnt[256];
  __shared__ u32 offs[256];
  __shared__ u32 basearr[256];
  const int b = blockIdx.x, t = threadIdx.x;
  u32 count = cursor[b];
  if (count > BCAP) count = BCAP;
  cnt[t] = 0;
  __syncthreads();
  const u32* pb = pairs + (size_t)b * BCAP;
  for (u32 i = t; i < count; i += 256) atomicAdd(&cnt[pb[i] & 255u], 1u);
  __syncthreads();
  const u32 my = cnt[t];
  offs[t] = my;
  __syncthreads();
  for (int d = 1; d < 256; d <<= 1) {
    u32 v = (t >= d) ? offs[t - d] : 0u;
    __syncthreads();
    offs[t] += v;
    __syncthreads();
  }
  const u32 excl = offs[t] - my;  // exclusive prefix
  const int node = (b << 8) + t;
  if (node < nrows) {
    RS[node] = b * BCAP + (int)excl;
    DEG[node] = (int)my;
  }
  basearr[t] = excl;
  cnt[t] = 0;
  __syncthreads();
  for (u32 i = t; i < count; i += 256) {
    u32 v = pb[i];
    u32 dl = v & 255u;
    u32 r = atomicAdd(&cnt[dl], 1u);
    csr[(size_t)b * BCAP + basearr[dl] + r] = v >> 8;
  }
}

// ---- aggregation: AGG[i] = f(row(i)) + sum_j f(row(j))
// MODE 0: row(i)=TBL[x[i]], f=id (layer 0).  MODE 1: row(i)=H[i], f=BN-affine+relu
// (scsh precomputed by bn_finalize). BN stays fused per-edge: r9 proved a separate
// per-node pass costs 13 us/layer vs ~5.5 fused. VALU cut via f32x2 packed math
// (v_pk_fma/max/add candidates) + high-half bf16 trick (u&0xffff0000, no shift).
// 3-deep load pipeline, one bool per iteration (r6 showed WIDE predication hurts,
// not depth). 32-bit byte offsets.
template <int MODE>
__global__ __launch_bounds__(256) void agg_kernel(
    const u16* __restrict__ Hsrc, const int* __restrict__ x, const u32* __restrict__ csr,
    const int* __restrict__ RS, const int* __restrict__ DEG, const float* __restrict__ scsh,
    u16* __restrict__ AGG, int nrows) {
  int node = blockIdx.x * 4 + (threadIdx.x >> 6);
  if (node >= nrows) return;
  const int lane = threadIdx.x & 63;
  const int grp = lane >> 4;  // neighbor sub-slot 0..3
  const int fl = lane & 15;   // 16B feature chunk
  const int deg = DEG[node];
  const u32* cl = csr + RS[node];
  const char* Hb = (const char*)Hsrc;
  const u32 flo = (u32)fl << 4;

  f32x2 sc2[4], sh2[4];
  if (MODE == 1) {
#pragma unroll
    for (int i = 0; i < 4; ++i) {
      sc2[i].x = scsh[fl * 8 + 2 * i];
      sc2[i].y = scsh[fl * 8 + 2 * i + 1];
      sh2[i].x = scsh[128 + fl * 8 + 2 * i];
      sh2[i].y = scsh[128 + fl * 8 + 2 * i + 1];
    }
  }
  f32x2 a2[4];
#pragma unroll
  for (int i = 0; i < 4; ++i) a2[i] = (f32x2)0.f;

#define ACCUM(vv)                                        \
  {                                                      \
    const u32* q = (const u32*)&(vv);                    \
    _Pragma("unroll") for (int i = 0; i < 4; ++i) {      \
      u32 u = q[i];                                      \
      f32x2 xv;                                          \
      xv.x = __builtin_bit_cast(float, u << 16);         \
      xv.y = __builtin_bit_cast(float, u & 0xffff0000u); \
      if (MODE == 1) {                                   \
        xv = xv * sc2[i] + sh2[i];                       \
        xv.x = xv.x > 0.f ? xv.x : 0.f;                  \
        xv.y = xv.y > 0.f ? xv.y : 0.f;                  \
      }                                                  \
      a2[i] += xv;                                       \
    }                                                    \
  }
#define ROWOFF(idx) ((((u32)(MODE == 0 ? x[(idx)] : (idx))) << 8) + flo)

  if (grp == 0) {
    uint4 v = *(const uint4*)(Hb + ROWOFF(node));
    ACCUM(v);
  }
  int j = grp;
  int cB = (j + 4 < deg) ? (int)cl[j + 4] : 0;
  int cC = (j + 8 < deg) ? (int)cl[j + 8] : 0;
  uint4 nv = make_uint4(0u, 0u, 0u, 0u), nv2 = make_uint4(0u, 0u, 0u, 0u);
  if (j < deg) nv = *(const uint4*)(Hb + ROWOFF((int)cl[j]));
  if (j + 4 < deg) nv2 = *(const uint4*)(Hb + ROWOFF(cB));
  while (j < deg) {
    uint4 cv = nv;
    nv = nv2;
    int cn = cC;
    cC = (j + 12 < deg) ? (int)cl[j + 12] : 0;
    nv2 = make_uint4(0u, 0u, 0u, 0u);
    if (j + 8 < deg) nv2 = *(const uint4*)(Hb + ROWOFF(cn));
    ACCUM(cv);
    j += 4;
  }
#undef ROWOFF
#undef ACCUM

#pragma unroll
  for (int i = 0; i < 4; ++i) {
    a2[i].x += __shfl_xor(a2[i].x, 16);
    a2[i].y += __shfl_xor(a2[i].y, 16);
    a2[i].x += __shfl_xor(a2[i].x, 32);
    a2[i].y += __shfl_xor(a2[i].y, 32);
  }
  if (grp == 0) {
    u32 o[4];
#pragma unroll
    for (int i = 0; i < 4; ++i) o[i] = (u32)f2bf(a2[i].x) | ((u32)f2bf(a2[i].y) << 16);
    *(uint4*)(AGG + (size_t)node * 128 + fl * 8) = *(uint4*)o;
  }
}

// ---- fused 2-layer MLP (bf16 MFMA), 64-row x 128-col tile per block, 4 waves
// Y = relu(X@W1+b1)@W2+b2 ; per-column sum/sumsq via same-address global atomics
// (proven cheap in r6; the "contention-free" PART+1-block-reduce cost 318 us in r7).
__global__ __launch_bounds__(256) void mlp_kernel(
    const u16* __restrict__ X, const u16* __restrict__ W1t, const float* __restrict__ b1,
    const u16* __restrict__ W2t, const float* __restrict__ b2, u16* __restrict__ Y,
    float* __restrict__ stats, int nrows) {
  __shared__ u16 Xs[64 * 136];
  __shared__ u16 Ts[64 * 136];
  const int t = threadIdx.x;
  const int row0 = blockIdx.x * 64;
  {
    const int seg = t & 15;
    const int rb = t >> 4;
#pragma unroll
    for (int p = 0; p < 4; ++p) {
      const int r = rb + p * 16;
      const int gr = row0 + r;
      uint4 v = make_uint4(0u, 0u, 0u, 0u);
      if (gr < nrows) v = *(const uint4*)(X + (size_t)gr * 128 + seg * 8);
      *(uint4*)(Xs + r * 136 + seg * 8) = v;
    }
  }
  __syncthreads();
  const int lane = t & 63;
  const int wave = t >> 6;
  const int n0 = wave * 32;
  const int nl = lane & 15;
  const int quad = lane >> 4;

  bf16x8 bw[2][4];
#pragma unroll
  for (int nt = 0; nt < 2; ++nt)
#pragma unroll
    for (int kk = 0; kk < 4; ++kk)
      bw[nt][kk] = *(const bf16x8*)(W1t + (size_t)(n0 + nt * 16 + nl) * 128 + kk * 32 + quad * 8);

  f32x4 acc[4][2];
#pragma unroll
  for (int mt = 0; mt < 4; ++mt) {
    acc[mt][0] = (f32x4)0.0f;
    acc[mt][1] = (f32x4)0.0f;
  }
#pragma unroll
  for (int kk = 0; kk < 4; ++kk) {
#pragma unroll
    for (int mt = 0; mt < 4; ++mt) {
      bf16x8 a = *(const bf16x8*)(Xs + (mt * 16 + nl) * 136 + kk * 32 + quad * 8);
      acc[mt][0] = MFMA_BF16(a, bw[0][kk], acc[mt][0]);
      acc[mt][1] = MFMA_BF16(a, bw[1][kk], acc[mt][1]);
    }
  }
  // epilogue 1: bias + relu -> Ts (bf16)
#pragma unroll
  for (int nt = 0; nt < 2; ++nt) {
    const int n = n0 + nt * 16 + nl;
    const float bias = b1[n];
#pragma unroll
    for (int mt = 0; mt < 4; ++mt)
#pragma unroll
      for (int r = 0; r < 4; ++r) {
        float v = acc[mt][nt][r] + bias;
        v = v > 0.f ? v : 0.f;
        Ts[(mt * 16 + quad * 4 + r) * 136 + n] = f2bf(v);
      }
  }
  __syncthreads();
  // GEMM2
#pragma unroll
  for (int nt = 0; nt < 2; ++nt)
#pragma unroll
    for (int kk = 0; kk < 4; ++kk)
      bw[nt][kk] = *(const bf16x8*)(W2t + (size_t)(n0 + nt * 16 + nl) * 128 + kk * 32 + quad * 8);
#pragma unroll
  for (int mt = 0; mt < 4; ++mt) {
    acc[mt][0] = (f32x4)0.0f;
    acc[mt][1] = (f32x4)0.0f;
  }
#pragma unroll
  for (int kk = 0; kk < 4; ++kk) {
#pragma unroll
    for (int mt = 0; mt < 4; ++mt) {
      bf16x8 a = *(const bf16x8*)(Ts + (mt * 16 + nl) * 136 + kk * 32 + quad * 8);
      acc[mt][0] = MFMA_BF16(a, bw[0][kk], acc[mt][0]);
      acc[mt][1] = MFMA_BF16(a, bw[1][kk], acc[mt][1]);
    }
  }
  // epilogue 2: bias, store Y (bf16), BN stats
  float ssum[2] = {0.f, 0.f}, ssq[2] = {0.f, 0.f};
#pragma unroll
  for (int nt = 0; nt < 2; ++nt) {
    const int n = n0 + nt * 16 + nl;
    const float bias = b2[n];
#pragma unroll
    for (int mt = 0; mt < 4; ++mt)
#pragma unroll
      for (int r = 0; r < 4; ++r) {
        const int row = row0 + mt * 16 + quad * 4 + r;
        float v = acc[mt][nt][r] + bias;
        if (row < nrows) {
          Y[(size_t)row * 128 + n] = f2bf(v);
          ssum[nt] += v;
          ssq[nt] += v * v;
        }
      }
  }
#pragma unroll
  for (int nt = 0; nt < 2; ++nt) {
    float s = ssum[nt], q = ssq[nt];
    s += __shfl_xor(s, 16);
    q += __shfl_xor(q, 16);
    s += __shfl_xor(s, 32);
    q += __shfl_xor(q, 32);
    if (quad == 0) {
      const int n = n0 + nt * 16 + nl;
      atomicAdd(&stats[n], s);
      atomicAdd(&stats[128 + n], q);
    }
  }
}

// ---- BN finalize: per-feature scale/shift from sums (tiny; ~free)
__global__ __launch_bounds__(128) void bn_finalize(const float* __restrict__ stats,
                                                   const float* __restrict__ g,
                                                   const float* __restrict__ be,
                                                   float* __restrict__ scsh, float invN) {
  int f = threadIdx.x;
  float mu = stats[f] * invN;
  float var = stats[128 + f] * invN - mu * mu;
  float rstd = rsqrtf(var + 1e-5f);
  float sc = rstd * g[f];
  scsh[f] = sc;
  scsh[128 + f] = be[f] - mu * sc;
}

// ---- pooling (fused layer-3 BN+relu via precomputed scsh) + final head, one block/graph
__global__ __launch_bounds__(256) void pool_final(
    const u16* __restrict__ Hh, const int* __restrict__ batch, const float* __restrict__ scsh,
    const float* __restrict__ f1w, const float* __restrict__ f1b, const float* __restrict__ f2w,
    const float* __restrict__ f2b, float* __restrict__ out, int nrows) {
  __shared__ float red[16][128];
  __shared__ float pr[128];
  __shared__ float tt[128];
  const int gid = blockIdx.x, t = threadIdx.x;
  int l = 0, r = nrows;
  while (l < r) {
    int m = (l + r) >> 1;
    if (batch[m] < gid) l = m + 1; else r = m;
  }
  const int s0 = l;
  r = nrows;
  while (l < r) {
    int m = (l + r) >> 1;
    if (batch[m] < gid + 1) l = m + 1; else r = m;
  }
  const int s1 = l;
  const int fl = t & 15;
  const int grp = t >> 4;
  float sc[8], sh[8];
#pragma unroll
  for (int i = 0; i < 8; ++i) {
    sc[i] = scsh[fl * 8 + i];
    sh[i] = scsh[128 + fl * 8 + i];
  }
  float a[8];
#pragma unroll
  for (int i = 0; i < 8; ++i) a[i] = 0.f;
  for (int i = s0 + grp; i < s1; i += 16) {
    uint4 v = *(const uint4*)(Hh + (size_t)i * 128 + fl * 8);
    const u16* pp = (const u16*)&v;
#pragma unroll
    for (int k = 0; k < 8; ++k) {
      float xv = bf2f(pp[k]) * sc[k] + sh[k];
      a[k] += xv > 0.f ? xv : 0.f;
    }
  }
#pragma unroll
  for (int k = 0; k < 8; ++k) red[grp][fl * 8 + k] = a[k];
  __syncthreads();
  if (t < 128) {
    float s = 0.f;
#pragma unroll
    for (int gg2 = 0; gg2 < 16; ++gg2) s += red[gg2][t];
    pr[t] = s;
  }
  __syncthreads();
  if (t < 128) {
    float s = f1b[t];
    for (int k = 0; k < 128; ++k) s += pr[k] * f1w[k * 128 + t];
    tt[t] = s > 0.f ? s : 0.f;
  }
  __syncthreads();
  if (t < 10) {
    float s2 = f2b[t];
    for (int k = 0; k < 128; ++k) s2 += tt[k] * f2w[k * 10 + t];
    out[gid * 10 + t] = s2;
  }
}

// ws layout (bytes):
//   H     @ 0          : 25,600,000  (bf16 node features)
//   AGG   @ 25,600,000 : 25,600,000  (bf16 aggregated, layer input tiles)
//   PAIRS @ 51,200,000 : 512*4608*4 = 9,437,184
//   CSR   @ 60,637,184 : 9,437,184
//   RS    @ 70,074,368 : 400,000
//   DEG   @ 70,474,368 : 400,000
//   CUR   @ 70,874,368 : 2,048       (zeroed)
//   STATS @ 70,876,416 : 3,072       (3 layers x 256 f32; zeroed, contiguous w/ CUR)
//   SCSH  @ 70,879,488 : 3,072       (3 layers x 256 f32; written by bn_finalize)
//   WT    @ 70,882,560 : 196,608
//   TBL   @ 71,079,168 : 128,000
extern "C" void kernel_launch(void* const* d_in, const int* in_sizes, int n_in, void* d_out,
                              int out_size, void* d_ws, size_t ws_size, hipStream_t stream) {
  const int* x = (const int*)d_in[0];
  const int* ei = (const int*)d_in[1];
  const int* batch = (const int*)d_in[2];
  const float* emb = (const float*)d_in[3];
  const float* iw1 = (const float*)d_in[4];
  const float* ib1 = (const float*)d_in[5];
  const float* iw2 = (const float*)d_in[6];
  const float* ib2 = (const float*)d_in[7];
  const float* f1w = (const float*)d_in[8];
  const float* f1b = (const float*)d_in[9];
  const float* f2w = (const float*)d_in[10];
  const float* f2b = (const float*)d_in[11];
  const float* cw1[3] = {(const float*)d_in[12], (const float*)d_in[18], (const float*)d_in[24]};
  const float* cb1[3] = {(const float*)d_in[13], (const float*)d_in[19], (const float*)d_in[25]};
  const float* cw2[3] = {(const float*)d_in[14], (const float*)d_in[20], (const float*)d_in[26]};
  const float* cb2[3] = {(const float*)d_in[15], (const float*)d_in[21], (const float*)d_in[27]};
  const float* gg[3] = {(const float*)d_in[16], (const float*)d_in[22], (const float*)d_in[28]};
  const float* bb[3] = {(const float*)d_in[17], (const float*)d_in[23], (const float*)d_in[29]};

  const int N_ = in_sizes[0];
  const int E_ = in_sizes[1] / 2;
  const int V_ = in_sizes[3] / 128;
  const int G_ = out_size / 10;
  const int NBUC = (N_ + 255) >> 8;
  const float invN = 1.0f / (float)N_;

  char* ws = (char*)d_ws;
  u16* H = (u16*)(ws + 0);
  u16* AGG = (u16*)(ws + 25600000);
  u32* PAIRS = (u32*)(ws + 51200000);
  u32* CSR = (u32*)(ws + 60637184);
  int* RS = (int*)(ws + 70074368);
  int* DEG = (int*)(ws + 70474368);
  u32* CUR = (u32*)(ws + 70874368);
  float* STATS = (float*)(ws + 70876416);
  float* SCSH = (float*)(ws + 70879488);
  u16* WT = (u16*)(ws + 70882560);
  u16* TBL = (u16*)(ws + 71079168);

  hipMemsetAsync(ws + 70874368, 0, 5120, stream);  // CUR + STATS

  prep_w6<<<384, 256, 0, stream>>>(cw1[0], cw2[0], cw1[1], cw2[1], cw1[2], cw2[2], WT);
  mlp0_table<<<V_, 128, 0, stream>>>(emb, iw1, ib1, iw2, ib2, TBL);
  bucket_scatter<<<(E_ + EPB - 1) / EPB, 256, 0, stream>>>(ei, ei + E_, PAIRS, CUR, E_, NBUC);
  csr_build<<<NBUC, 256, 0, stream>>>(PAIRS, CUR, CSR, RS, DEG, N_);

  const int ablk = (N_ + 3) / 4;
  const int mblk = (N_ + 63) / 64;
  for (int l = 0; l < 3; ++l) {
    const u16* W1 = WT + (size_t)l * 32768;
    const u16* W2 = WT + (size_t)l * 32768 + 16384;
    if (l == 0)
      agg_kernel<0><<<ablk, 256, 0, stream>>>(TBL, x, CSR, RS, DEG, nullptr, AGG, N_);
    else
      agg_kernel<1><<<ablk, 256, 0, stream>>>(H, nullptr, CSR, RS, DEG, SCSH + (l - 1) * 256,
                                              AGG, N_);
    mlp_kernel<<<mblk, 256, 0, stream>>>(AGG, W1, cb1[l], W2, cb2[l], H, STATS + l * 256, N_);
    bn_finalize<<<1, 128, 0, stream>>>(STATS + l * 256, gg[l], bb[l], SCSH + l * 256, invN);
  }
  pool_final<<<G_, 256, 0, stream>>>(H, batch, SCSH + 2 * 256, f1w, f1b, f2w, f2b,
                                     (float*)d_out, N_);
}

// Round 11
// 536.825 us; speedup vs baseline: 1.0627x; 1.0365x over previous
//
#include <hip/hip_runtime.h>

typedef unsigned short u16;
typedef unsigned int u32;
typedef __bf16 bf16x8 __attribute__((ext_vector_type(8)));
typedef float f32x4 __attribute__((ext_vector_type(4)));

#define MFMA_BF16(a, b, c) __builtin_amdgcn_mfma_f32_16x16x32_bf16(a, b, c, 0, 0, 0)

#define NBUC_MAX 512
#define BCAP 4608
#define EPB 8192  // edges per block in bucket_scatter

__device__ __forceinline__ float bf2f(u16 h) {
  u32 u = ((u32)h) << 16;
  return __builtin_bit_cast(float, u);
}
__device__ __forceinline__ u16 f2bf(float f) {
  u32 u = __builtin_bit_cast(u32, f);
  u += 0x7fffu + ((u >> 16) & 1u);
  return (u16)(u >> 16);
}

// ---- weight prep: 6 conv weights fp32 [k][n] -> bf16 transposed [n][k], one dispatch
__global__ __launch_bounds__(256) void prep_w6(const float* __restrict__ w0,
                                               const float* __restrict__ w1,
                                               const float* __restrict__ w2,
                                               const float* __restrict__ w3,
                                               const float* __restrict__ w4,
                                               const float* __restrict__ w5,
                                               u16* __restrict__ wt) {
  const int which = blockIdx.x >> 6;
  const float* w = which == 0 ? w0 : which == 1 ? w1 : which == 2 ? w2
                  : which == 3 ? w3 : which == 4 ? w4 : w5;
  int t = (blockIdx.x & 63) * 256 + threadIdx.x;  // 16384 elems per matrix
  int n = t >> 7, k = t & 127;
  wt[which * 16384 + n * 128 + k] = f2bf(w[k * 128 + n]);
}

// ---- initial MLP applied to the 500-row embedding table (h0 = table2[x])
__global__ __launch_bounds__(128) void mlp0_table(
    const float* __restrict__ emb, const float* __restrict__ w1, const float* __restrict__ b1,
    const float* __restrict__ w2, const float* __restrict__ b2, u16* __restrict__ table) {
  __shared__ float e[128];
  __shared__ float tt[128];
  int r = blockIdx.x, j = threadIdx.x;
  e[j] = emb[r * 128 + j];
  __syncthreads();
  float s = b1[j];
  for (int k = 0; k < 128; ++k) s += e[k] * w1[k * 128 + j];
  tt[j] = s > 0.f ? s : 0.f;
  __syncthreads();
  float s2 = b2[j];
  for (int k = 0; k < 128; ++k) s2 += tt[k] * w2[k * 128 + j];
  table[r * 128 + j] = f2bf(s2);
}

// ---- pass 1: bucket edges by dst>>8, packed (src<<8)|dloc. No LDS staging; LDS = 4 KB.
__global__ __launch_bounds__(256) void bucket_scatter(const int* __restrict__ src,
                                                      const int* __restrict__ dst,
                                                      u32* __restrict__ pairs,
                                                      u32* __restrict__ cursor, int E_, int nbuc) {
  __shared__ u32 lcnt[NBUC_MAX];
  __shared__ u32 lbase[NBUC_MAX];
  const int t = threadIdx.x;
  for (int b = t; b < NBUC_MAX; b += 256) lcnt[b] = 0;
  __syncthreads();
  const int e0 = blockIdx.x * EPB;
#pragma unroll
  for (int it = 0; it < EPB / 256; ++it) {
    int e = e0 + it * 256 + t;
    if (e < E_) atomicAdd(&lcnt[((u32)dst[e]) >> 8], 1u);
  }
  __syncthreads();
  for (int b = t; b < nbuc; b += 256) {
    u32 c = lcnt[b];
    lbase[b] = c ? atomicAdd(&cursor[b], c) : 0u;
    lcnt[b] = 0;
  }
  __syncthreads();
#pragma unroll
  for (int it = 0; it < EPB / 256; ++it) {
    int e = e0 + it * 256 + t;
    if (e < E_) {
      int d = dst[e];
      u32 b = ((u32)d) >> 8;
      u32 r = atomicAdd(&lcnt[b], 1u);
      u32 p = lbase[b] + r;
      if (p < BCAP) pairs[(size_t)b * BCAP + p] = (((u32)src[e]) << 8) | (u32)(d & 255);
    }
  }
}

// ---- pass 2: per-bucket exact CSR (256 nodes/bucket): LDS count + scan + rank scatter
__global__ __launch_bounds__(256) void csr_build(const u32* __restrict__ pairs,
                                                 const u32* __restrict__ cursor,
                                                 u32* __restrict__ csr, int* __restrict__ RS,
                                                 int* __restrict__ DEG, int nrows) {
  __shared__ u32 cnt[256];
  __shared__ u32 offs[256];
  __shared__ u32 basearr[256];
  const int b = blockIdx.x, t = threadIdx.x;
  u32 count = cursor[b];
  if (count > BCAP) count = BCAP;
  cnt[t] = 0;
  __syncthreads();
  const u32* pb = pairs + (size_t)b * BCAP;
  for (u32 i = t; i < count; i += 256) atomicAdd(&cnt[pb[i] & 255u], 1u);
  __syncthreads();
  const u32 my = cnt[t];
  offs[t] = my;
  __syncthreads();
  for (int d = 1; d < 256; d <<= 1) {
    u32 v = (t >= d) ? offs[t - d] : 0u;
    __syncthreads();
    offs[t] += v;
    __syncthreads();
  }
  const u32 excl = offs[t] - my;  // exclusive prefix
  const int node = (b << 8) + t;
  if (node < nrows) {
    RS[node] = b * BCAP + (int)excl;
    DEG[node] = (int)my;
  }
  basearr[t] = excl;
  cnt[t] = 0;
  __syncthreads();
  for (u32 i = t; i < count; i += 256) {
    u32 v = pb[i];
    u32 dl = v & 255u;
    u32 r = atomicAdd(&cnt[dl], 1u);
    csr[(size_t)b * BCAP + basearr[dl] + r] = v >> 8;
  }
}

// ---- aggregation (exact r8 config — best known: 69.2 us, VALU 65%):
// AGG[i] = f(row(i)) + sum_j f(row(j)).  MODE 0: row(i)=TBL[x[i]], f=id.
// MODE 1: row(i)=H[i], f=BN-affine+relu (scsh precomputed).  Fused per-edge BN is
// net-cheaper than a separate pass (r9: -11 agg vs +26 bn_apply).  Scalar f32 math
// (r10's manual f32x2 "packed" regressed: no v_pk lowering, VGPR 24->28, VALU 70%).
// 2-deep pipeline (r6: wider predication regresses). 32-bit byte offsets.
template <int MODE>
__global__ __launch_bounds__(256) void agg_kernel(
    const u16* __restrict__ Hsrc, const int* __restrict__ x, const u32* __restrict__ csr,
    const int* __restrict__ RS, const int* __restrict__ DEG, const float* __restrict__ scsh,
    u16* __restrict__ AGG, int nrows) {
  int node = blockIdx.x * 4 + (threadIdx.x >> 6);
  if (node >= nrows) return;
  const int lane = threadIdx.x & 63;
  const int grp = lane >> 4;  // neighbor sub-slot 0..3
  const int fl = lane & 15;   // 16B feature chunk
  const int deg = DEG[node];
  const u32* cl = csr + RS[node];
  const char* Hb = (const char*)Hsrc;
  const u32 flo = (u32)fl << 4;

  float sc[8], sh[8];
  if (MODE == 1) {
#pragma unroll
    for (int i = 0; i < 8; ++i) {
      sc[i] = scsh[fl * 8 + i];
      sh[i] = scsh[128 + fl * 8 + i];
    }
  }
  float a[8];
#pragma unroll
  for (int i = 0; i < 8; ++i) a[i] = 0.f;

#define ACCUM(vv)                                   \
  {                                                 \
    const u16* p = (const u16*)&(vv);               \
    _Pragma("unroll") for (int i = 0; i < 8; ++i) { \
      float xv = bf2f(p[i]);                        \
      if (MODE == 1) {                              \
        xv = xv * sc[i] + sh[i];                    \
        xv = xv > 0.f ? xv : 0.f;                   \
      }                                             \
      a[i] += xv;                                   \
    }                                               \
  }
#define ROWOFF(idx) ((((u32)(MODE == 0 ? x[(idx)] : (idx))) << 8) + flo)

  if (grp == 0) {
    uint4 v = *(const uint4*)(Hb + ROWOFF(node));
    ACCUM(v);
  }
  int j = grp;
  int cA = (j < deg) ? (int)cl[j] : 0;
  int cB = (j + 4 < deg) ? (int)cl[j + 4] : 0;
  uint4 nv = make_uint4(0u, 0u, 0u, 0u);
  if (j < deg) nv = *(const uint4*)(Hb + ROWOFF(cA));
  while (j < deg) {
    uint4 cv = nv;
    int cn = cB;
    cB = (j + 8 < deg) ? (int)cl[j + 8] : 0;
    if (j + 4 < deg) nv = *(const uint4*)(Hb + ROWOFF(cn));
    ACCUM(cv);
    j += 4;
  }
#undef ROWOFF
#undef ACCUM

#pragma unroll
  for (int i = 0; i < 8; ++i) {
    a[i] += __shfl_xor(a[i], 16);
    a[i] += __shfl_xor(a[i], 32);
  }
  if (grp == 0) {
    u32 o[4];
#pragma unroll
    for (int i = 0; i < 4; ++i) o[i] = (u32)f2bf(a[2 * i]) | ((u32)f2bf(a[2 * i + 1]) << 16);
    *(uint4*)(AGG + (size_t)node * 128 + fl * 8) = *(uint4*)o;
  }
}

// ---- fused 2-layer MLP (bf16 MFMA), 128-row x 128-col tile, 4 waves, T in-place
// over Xs (r4-proven with extra barrier). vs r8's 64-row tile: half the blocks,
// 2x MFMA per barrier, half the atomic-tail depth, LDS still 34.8 KB (4 blocks/CU).
// Per-column sum/sumsq via same-address global atomics (proven cheap r6; the
// "contention-free" PART+1-block-reduce cost 318 us in r7).
__global__ __launch_bounds__(256) void mlp_kernel(
    const u16* __restrict__ X, const u16* __restrict__ W1t, const float* __restrict__ b1,
    const u16* __restrict__ W2t, const float* __restrict__ b2, u16* __restrict__ Y,
    float* __restrict__ stats, int nrows) {
  __shared__ u16 Xs[128 * 136];
  const int t = threadIdx.x;
  const int row0 = blockIdx.x * 128;
  {
    const int seg = t & 15;
    const int rb = t >> 4;
#pragma unroll
    for (int p = 0; p < 8; ++p) {
      const int r = rb + p * 16;
      const int gr = row0 + r;
      uint4 v = make_uint4(0u, 0u, 0u, 0u);
      if (gr < nrows) v = *(const uint4*)(X + (size_t)gr * 128 + seg * 8);
      *(uint4*)(Xs + r * 136 + seg * 8) = v;
    }
  }
  __syncthreads();
  const int lane = t & 63;
  const int wave = t >> 6;
  const int n0 = wave * 32;
  const int nl = lane & 15;
  const int quad = lane >> 4;

  bf16x8 bw[2][4];
#pragma unroll
  for (int nt = 0; nt < 2; ++nt)
#pragma unroll
    for (int kk = 0; kk < 4; ++kk)
      bw[nt][kk] = *(const bf16x8*)(W1t + (size_t)(n0 + nt * 16 + nl) * 128 + kk * 32 + quad * 8);

  f32x4 acc[8][2];
#pragma unroll
  for (int mt = 0; mt < 8; ++mt) {
    acc[mt][0] = (f32x4)0.0f;
    acc[mt][1] = (f32x4)0.0f;
  }
#pragma unroll
  for (int kk = 0; kk < 4; ++kk) {
#pragma unroll
    for (int mt = 0; mt < 8; ++mt) {
      bf16x8 a = *(const bf16x8*)(Xs + (mt * 16 + nl) * 136 + kk * 32 + quad * 8);
      acc[mt][0] = MFMA_BF16(a, bw[0][kk], acc[mt][0]);
      acc[mt][1] = MFMA_BF16(a, bw[1][kk], acc[mt][1]);
    }
  }
  __syncthreads();  // all GEMM1 A-reads complete before overwriting Xs with T
  // epilogue 1: bias + relu -> Xs (in place, bf16)
#pragma unroll
  for (int nt = 0; nt < 2; ++nt) {
    const int n = n0 + nt * 16 + nl;
    const float bias = b1[n];
#pragma unroll
    for (int mt = 0; mt < 8; ++mt)
#pragma unroll
      for (int r = 0; r < 4; ++r) {
        float v = acc[mt][nt][r] + bias;
        v = v > 0.f ? v : 0.f;
        Xs[(mt * 16 + quad * 4 + r) * 136 + n] = f2bf(v);
      }
  }
  __syncthreads();
  // GEMM2
#pragma unroll
  for (int nt = 0; nt < 2; ++nt)
#pragma unroll
    for (int kk = 0; kk < 4; ++kk)
      bw[nt][kk] = *(const bf16x8*)(W2t + (size_t)(n0 + nt * 16 + nl) * 128 + kk * 32 + quad * 8);
#pragma unroll
  for (int mt = 0; mt < 8; ++mt) {
    acc[mt][0] = (f32x4)0.0f;
    acc[mt][1] = (f32x4)0.0f;
  }
#pragma unroll
  for (int kk = 0; kk < 4; ++kk) {
#pragma unroll
    for (int mt = 0; mt < 8; ++mt) {
      bf16x8 a = *(const bf16x8*)(Xs + (mt * 16 + nl) * 136 + kk * 32 + quad * 8);
      acc[mt][0] = MFMA_BF16(a, bw[0][kk], acc[mt][0]);
      acc[mt][1] = MFMA_BF16(a, bw[1][kk], acc[mt][1]);
    }
  }
  // epilogue 2: bias, store Y (bf16), BN stats
  float ssum[2] = {0.f, 0.f}, ssq[2] = {0.f, 0.f};
#pragma unroll
  for (int nt = 0; nt < 2; ++nt) {
    const int n = n0 + nt * 16 + nl;
    const float bias = b2[n];
#pragma unroll
    for (int mt = 0; mt < 8; ++mt)
#pragma unroll
      for (int r = 0; r < 4; ++r) {
        const int row = row0 + mt * 16 + quad * 4 + r;
        float v = acc[mt][nt][r] + bias;
        if (row < nrows) {
          Y[(size_t)row * 128 + n] = f2bf(v);
          ssum[nt] += v;
          ssq[nt] += v * v;
        }
      }
  }
#pragma unroll
  for (int nt = 0; nt < 2; ++nt) {
    float s = ssum[nt], q = ssq[nt];
    s += __shfl_xor(s, 16);
    q += __shfl_xor(q, 16);
    s += __shfl_xor(s, 32);
    q += __shfl_xor(q, 32);
    if (quad == 0) {
      const int n = n0 + nt * 16 + nl;
      atomicAdd(&stats[n], s);
      atomicAdd(&stats[128 + n], q);
    }
  }
}

// ---- BN finalize: per-feature scale/shift from sums (tiny; ~free)
__global__ __launch_bounds__(128) void bn_finalize(const float* __restrict__ stats,
                                                   const float* __restrict__ g,
                                                   const float* __restrict__ be,
                                                   float* __restrict__ scsh, float invN) {
  int f = threadIdx.x;
  float mu = stats[f] * invN;
  float var = stats[128 + f] * invN - mu * mu;
  float rstd = rsqrtf(var + 1e-5f);
  float sc = rstd * g[f];
  scsh[f] = sc;
  scsh[128 + f] = be[f] - mu * sc;
}

// ---- pooling (fused layer-3 BN+relu via precomputed scsh) + final head, one block/graph
__global__ __launch_bounds__(256) void pool_final(
    const u16* __restrict__ Hh, const int* __restrict__ batch, const float* __restrict__ scsh,
    const float* __restrict__ f1w, const float* __restrict__ f1b, const float* __restrict__ f2w,
    const float* __restrict__ f2b, float* __restrict__ out, int nrows) {
  __shared__ float red[16][128];
  __shared__ float pr[128];
  __shared__ float tt[128];
  const int gid = blockIdx.x, t = threadIdx.x;
  int l = 0, r = nrows;
  while (l < r) {
    int m = (l + r) >> 1;
    if (batch[m] < gid) l = m + 1; else r = m;
  }
  const int s0 = l;
  r = nrows;
  while (l < r) {
    int m = (l + r) >> 1;
    if (batch[m] < gid + 1) l = m + 1; else r = m;
  }
  const int s1 = l;
  const int fl = t & 15;
  const int grp = t >> 4;
  float sc[8], sh[8];
#pragma unroll
  for (int i = 0; i < 8; ++i) {
    sc[i] = scsh[fl * 8 + i];
    sh[i] = scsh[128 + fl * 8 + i];
  }
  float a[8];
#pragma unroll
  for (int i = 0; i < 8; ++i) a[i] = 0.f;
  for (int i = s0 + grp; i < s1; i += 16) {
    uint4 v = *(const uint4*)(Hh + (size_t)i * 128 + fl * 8);
    const u16* pp = (const u16*)&v;
#pragma unroll
    for (int k = 0; k < 8; ++k) {
      float xv = bf2f(pp[k]) * sc[k] + sh[k];
      a[k] += xv > 0.f ? xv : 0.f;
    }
  }
#pragma unroll
  for (int k = 0; k < 8; ++k) red[grp][fl * 8 + k] = a[k];
  __syncthreads();
  if (t < 128) {
    float s = 0.f;
#pragma unroll
    for (int gg2 = 0; gg2 < 16; ++gg2) s += red[gg2][t];
    pr[t] = s;
  }
  __syncthreads();
  if (t < 128) {
    float s = f1b[t];
    for (int k = 0; k < 128; ++k) s += pr[k] * f1w[k * 128 + t];
    tt[t] = s > 0.f ? s : 0.f;
  }
  __syncthreads();
  if (t < 10) {
    float s2 = f2b[t];
    for (int k = 0; k < 128; ++k) s2 += tt[k] * f2w[k * 10 + t];
    out[gid * 10 + t] = s2;
  }
}

// ws layout (bytes):
//   H     @ 0          : 25,600,000  (bf16 node features)
//   AGG   @ 25,600,000 : 25,600,000  (bf16 aggregated, layer input tiles)
//   PAIRS @ 51,200,000 : 512*4608*4 = 9,437,184
//   CSR   @ 60,637,184 : 9,437,184
//   RS    @ 70,074,368 : 400,000
//   DEG   @ 70,474,368 : 400,000
//   CUR   @ 70,874,368 : 2,048       (zeroed)
//   STATS @ 70,876,416 : 3,072       (3 layers x 256 f32; zeroed, contiguous w/ CUR)
//   SCSH  @ 70,879,488 : 3,072       (3 layers x 256 f32; written by bn_finalize)
//   WT    @ 70,882,560 : 196,608
//   TBL   @ 71,079,168 : 128,000
extern "C" void kernel_launch(void* const* d_in, const int* in_sizes, int n_in, void* d_out,
                              int out_size, void* d_ws, size_t ws_size, hipStream_t stream) {
  const int* x = (const int*)d_in[0];
  const int* ei = (const int*)d_in[1];
  const int* batch = (const int*)d_in[2];
  const float* emb = (const float*)d_in[3];
  const float* iw1 = (const float*)d_in[4];
  const float* ib1 = (const float*)d_in[5];
  const float* iw2 = (const float*)d_in[6];
  const float* ib2 = (const float*)d_in[7];
  const float* f1w = (const float*)d_in[8];
  const float* f1b = (const float*)d_in[9];
  const float* f2w = (const float*)d_in[10];
  const float* f2b = (const float*)d_in[11];
  const float* cw1[3] = {(const float*)d_in[12], (const float*)d_in[18], (const float*)d_in[24]};
  const float* cb1[3] = {(const float*)d_in[13], (const float*)d_in[19], (const float*)d_in[25]};
  const float* cw2[3] = {(const float*)d_in[14], (const float*)d_in[20], (const float*)d_in[26]};
  const float* cb2[3] = {(const float*)d_in[15], (const float*)d_in[21], (const float*)d_in[27]};
  const float* gg[3] = {(const float*)d_in[16], (const float*)d_in[22], (const float*)d_in[28]};
  const float* bb[3] = {(const float*)d_in[17], (const float*)d_in[23], (const float*)d_in[29]};

  const int N_ = in_sizes[0];
  const int E_ = in_sizes[1] / 2;
  const int V_ = in_sizes[3] / 128;
  const int G_ = out_size / 10;
  const int NBUC = (N_ + 255) >> 8;
  const float invN = 1.0f / (float)N_;

  char* ws = (char*)d_ws;
  u16* H = (u16*)(ws + 0);
  u16* AGG = (u16*)(ws + 25600000);
  u32* PAIRS = (u32*)(ws + 51200000);
  u32* CSR = (u32*)(ws + 60637184);
  int* RS = (int*)(ws + 70074368);
  int* DEG = (int*)(ws + 70474368);
  u32* CUR = (u32*)(ws + 70874368);
  float* STATS = (float*)(ws + 70876416);
  float* SCSH = (float*)(ws + 70879488);
  u16* WT = (u16*)(ws + 70882560);
  u16* TBL = (u16*)(ws + 71079168);

  hipMemsetAsync(ws + 70874368, 0, 5120, stream);  // CUR + STATS

  prep_w6<<<384, 256, 0, stream>>>(cw1[0], cw2[0], cw1[1], cw2[1], cw1[2], cw2[2], WT);
  mlp0_table<<<V_, 128, 0, stream>>>(emb, iw1, ib1, iw2, ib2, TBL);
  bucket_scatter<<<(E_ + EPB - 1) / EPB, 256, 0, stream>>>(ei, ei + E_, PAIRS, CUR, E_, NBUC);
  csr_build<<<NBUC, 256, 0, stream>>>(PAIRS, CUR, CSR, RS, DEG, N_);

  const int ablk = (N_ + 3) / 4;
  const int mblk = (N_ + 127) / 128;
  for (int l = 0; l < 3; ++l) {
    const u16* W1 = WT + (size_t)l * 32768;
    const u16* W2 = WT + (size_t)l * 32768 + 16384;
    if (l == 0)
      agg_kernel<0><<<ablk, 256, 0, stream>>>(TBL, x, CSR, RS, DEG, nullptr, AGG, N_);
    else
      agg_kernel<1><<<ablk, 256, 0, stream>>>(H, nullptr, CSR, RS, DEG, SCSH + (l - 1) * 256,
                                              AGG, N_);
    mlp_kernel<<<mblk, 256, 0, stream>>>(AGG, W1, cb1[l], W2, cb2[l], H, STATS + l * 256, N_);
    bn_finalize<<<1, 128, 0, stream>>>(STATS + l * 256, gg[l], bb[l], SCSH + l * 256, invN);
  }
  pool_final<<<G_, 256, 0, stream>>>(H, batch, SCSH + 2 * 256, f1w, f1b, f2w, f2b,
                                     (float*)d_out, N_);
}

// Round 12
// 509.696 us; speedup vs baseline: 1.1193x; 1.0532x over previous
//
#include <hip/hip_runtime.h>

typedef unsigned short u16;
typedef unsigned int u32;
typedef __bf16 bf16x8 __attribute__((ext_vector_type(8)));
typedef float f32x4 __attribute__((ext_vector_type(4)));

#define MFMA_BF16(a, b, c) __builtin_amdgcn_mfma_f32_16x16x32_bf16(a, b, c, 0, 0, 0)

#define NBUC_MAX 512
#define BCAP 4608
#define EPB 2048  // edges per block in bucket_scatter (8192 gave only 196 blocks = 0.77/CU)

__device__ __forceinline__ float bf2f(u16 h) {
  u32 u = ((u32)h) << 16;
  return __builtin_bit_cast(float, u);
}
__device__ __forceinline__ u16 f2bf(float f) {
  u32 u = __builtin_bit_cast(u32, f);
  u += 0x7fffu + ((u >> 16) & 1u);
  return (u16)(u >> 16);
}

// ---- weight prep: 6 conv weights fp32 [k][n] -> bf16 transposed [n][k], one dispatch
__global__ __launch_bounds__(256) void prep_w6(const float* __restrict__ w0,
                                               const float* __restrict__ w1,
                                               const float* __restrict__ w2,
                                               const float* __restrict__ w3,
                                               const float* __restrict__ w4,
                                               const float* __restrict__ w5,
                                               u16* __restrict__ wt) {
  const int which = blockIdx.x >> 6;
  const float* w = which == 0 ? w0 : which == 1 ? w1 : which == 2 ? w2
                  : which == 3 ? w3 : which == 4 ? w4 : w5;
  int t = (blockIdx.x & 63) * 256 + threadIdx.x;  // 16384 elems per matrix
  int n = t >> 7, k = t & 127;
  wt[which * 16384 + n * 128 + k] = f2bf(w[k * 128 + n]);
}

// ---- initial MLP applied to the 500-row embedding table (h0 = table2[x])
__global__ __launch_bounds__(128) void mlp0_table(
    const float* __restrict__ emb, const float* __restrict__ w1, const float* __restrict__ b1,
    const float* __restrict__ w2, const float* __restrict__ b2, u16* __restrict__ table) {
  __shared__ float e[128];
  __shared__ float tt[128];
  int r = blockIdx.x, j = threadIdx.x;
  e[j] = emb[r * 128 + j];
  __syncthreads();
  float s = b1[j];
  for (int k = 0; k < 128; ++k) s += e[k] * w1[k * 128 + j];
  tt[j] = s > 0.f ? s : 0.f;
  __syncthreads();
  float s2 = b2[j];
  for (int k = 0; k < 128; ++k) s2 += tt[k] * w2[k * 128 + j];
  table[r * 128 + j] = f2bf(s2);
}

// ---- pass 1: bucket edges by dst>>8, packed (src<<8)|dloc. No LDS staging; LDS = 4 KB.
__global__ __launch_bounds__(256) void bucket_scatter(const int* __restrict__ src,
                                                      const int* __restrict__ dst,
                                                      u32* __restrict__ pairs,
                                                      u32* __restrict__ cursor, int E_, int nbuc) {
  __shared__ u32 lcnt[NBUC_MAX];
  __shared__ u32 lbase[NBUC_MAX];
  const int t = threadIdx.x;
  for (int b = t; b < NBUC_MAX; b += 256) lcnt[b] = 0;
  __syncthreads();
  const int e0 = blockIdx.x * EPB;
#pragma unroll
  for (int it = 0; it < EPB / 256; ++it) {
    int e = e0 + it * 256 + t;
    if (e < E_) atomicAdd(&lcnt[((u32)dst[e]) >> 8], 1u);
  }
  __syncthreads();
  for (int b = t; b < nbuc; b += 256) {
    u32 c = lcnt[b];
    lbase[b] = c ? atomicAdd(&cursor[b], c) : 0u;
    lcnt[b] = 0;
  }
  __syncthreads();
#pragma unroll
  for (int it = 0; it < EPB / 256; ++it) {
    int e = e0 + it * 256 + t;
    if (e < E_) {
      int d = dst[e];
      u32 b = ((u32)d) >> 8;
      u32 r = atomicAdd(&lcnt[b], 1u);
      u32 p = lbase[b] + r;
      if (p < BCAP) pairs[(size_t)b * BCAP + p] = (((u32)src[e]) << 8) | (u32)(d & 255);
    }
  }
}

// ---- pass 2: per-bucket exact CSR (256 nodes/bucket): LDS count + scan + rank scatter
__global__ __launch_bounds__(256) void csr_build(const u32* __restrict__ pairs,
                                                 const u32* __restrict__ cursor,
                                                 u32* __restrict__ csr, int* __restrict__ RS,
                                                 int* __restrict__ DEG, int nrows) {
  __shared__ u32 cnt[256];
  __shared__ u32 offs[256];
  __shared__ u32 basearr[256];
  const int b = blockIdx.x, t = threadIdx.x;
  u32 count = cursor[b];
  if (count > BCAP) count = BCAP;
  cnt[t] = 0;
  __syncthreads();
  const u32* pb = pairs + (size_t)b * BCAP;
  for (u32 i = t; i < count; i += 256) atomicAdd(&cnt[pb[i] & 255u], 1u);
  __syncthreads();
  const u32 my = cnt[t];
  offs[t] = my;
  __syncthreads();
  for (int d = 1; d < 256; d <<= 1) {
    u32 v = (t >= d) ? offs[t - d] : 0u;
    __syncthreads();
    offs[t] += v;
    __syncthreads();
  }
  const u32 excl = offs[t] - my;  // exclusive prefix
  const int node = (b << 8) + t;
  if (node < nrows) {
    RS[node] = b * BCAP + (int)excl;
    DEG[node] = (int)my;
  }
  basearr[t] = excl;
  cnt[t] = 0;
  __syncthreads();
  for (u32 i = t; i < count; i += 256) {
    u32 v = pb[i];
    u32 dl = v & 255u;
    u32 r = atomicAdd(&cnt[dl], 1u);
    csr[(size_t)b * BCAP + basearr[dl] + r] = v >> 8;
  }
}

// ---- aggregation (exact r8/r11 config — best known: 69.2 us, VALU 65%):
// AGG[i] = f(row(i)) + sum_j f(row(j)).  MODE 0: row(i)=TBL[x[i]], f=id.
// MODE 1: row(i)=H[i], f=BN-affine+relu (scsh precomputed).  Fused per-edge BN is
// net-cheaper than a separate pass (r9). Scalar f32 math (r10 packed regressed).
// 2-deep pipeline (r6: wider predication regresses). 32-bit byte offsets.
template <int MODE>
__global__ __launch_bounds__(256) void agg_kernel(
    const u16* __restrict__ Hsrc, const int* __restrict__ x, const u32* __restrict__ csr,
    const int* __restrict__ RS, const int* __restrict__ DEG, const float* __restrict__ scsh,
    u16* __restrict__ AGG, int nrows) {
  int node = blockIdx.x * 4 + (threadIdx.x >> 6);
  if (node >= nrows) return;
  const int lane = threadIdx.x & 63;
  const int grp = lane >> 4;  // neighbor sub-slot 0..3
  const int fl = lane & 15;   // 16B feature chunk
  const int deg = DEG[node];
  const u32* cl = csr + RS[node];
  const char* Hb = (const char*)Hsrc;
  const u32 flo = (u32)fl << 4;

  float sc[8], sh[8];
  if (MODE == 1) {
#pragma unroll
    for (int i = 0; i < 8; ++i) {
      sc[i] = scsh[fl * 8 + i];
      sh[i] = scsh[128 + fl * 8 + i];
    }
  }
  float a[8];
#pragma unroll
  for (int i = 0; i < 8; ++i) a[i] = 0.f;

#define ACCUM(vv)                                   \
  {                                                 \
    const u16* p = (const u16*)&(vv);               \
    _Pragma("unroll") for (int i = 0; i < 8; ++i) { \
      float xv = bf2f(p[i]);                        \
      if (MODE == 1) {                              \
        xv = xv * sc[i] + sh[i];                    \
        xv = xv > 0.f ? xv : 0.f;                   \
      }                                             \
      a[i] += xv;                                   \
    }                                               \
  }
#define ROWOFF(idx) ((((u32)(MODE == 0 ? x[(idx)] : (idx))) << 8) + flo)

  if (grp == 0) {
    uint4 v = *(const uint4*)(Hb + ROWOFF(node));
    ACCUM(v);
  }
  int j = grp;
  int cA = (j < deg) ? (int)cl[j] : 0;
  int cB = (j + 4 < deg) ? (int)cl[j + 4] : 0;
  uint4 nv = make_uint4(0u, 0u, 0u, 0u);
  if (j < deg) nv = *(const uint4*)(Hb + ROWOFF(cA));
  while (j < deg) {
    uint4 cv = nv;
    int cn = cB;
    cB = (j + 8 < deg) ? (int)cl[j + 8] : 0;
    if (j + 4 < deg) nv = *(const uint4*)(Hb + ROWOFF(cn));
    ACCUM(cv);
    j += 4;
  }
#undef ROWOFF
#undef ACCUM

#pragma unroll
  for (int i = 0; i < 8; ++i) {
    a[i] += __shfl_xor(a[i], 16);
    a[i] += __shfl_xor(a[i], 32);
  }
  if (grp == 0) {
    u32 o[4];
#pragma unroll
    for (int i = 0; i < 4; ++i) o[i] = (u32)f2bf(a[2 * i]) | ((u32)f2bf(a[2 * i + 1]) << 16);
    *(uint4*)(AGG + (size_t)node * 128 + fl * 8) = *(uint4*)o;
  }
}

// ---- fused 2-layer MLP (bf16 MFMA), 128-row x 128-col tile, 4 waves, T in-place
// over Xs. BN stats -> PART[block][256] plain stores: r7-vs-r8 cross-round isolation
// showed the same-address atomic tail costs ~28 us/layer @1563 blocks (~14 @782);
// contention-free stores + parallel column reduce replace it.
__global__ __launch_bounds__(256) void mlp_kernel(
    const u16* __restrict__ X, const u16* __restrict__ W1t, const float* __restrict__ b1,
    const u16* __restrict__ W2t, const float* __restrict__ b2, u16* __restrict__ Y,
    float* __restrict__ part, int nrows) {
  __shared__ u16 Xs[128 * 136];
  const int t = threadIdx.x;
  const int row0 = blockIdx.x * 128;
  {
    const int seg = t & 15;
    const int rb = t >> 4;
#pragma unroll
    for (int p = 0; p < 8; ++p) {
      const int r = rb + p * 16;
      const int gr = row0 + r;
      uint4 v = make_uint4(0u, 0u, 0u, 0u);
      if (gr < nrows) v = *(const uint4*)(X + (size_t)gr * 128 + seg * 8);
      *(uint4*)(Xs + r * 136 + seg * 8) = v;
    }
  }
  __syncthreads();
  const int lane = t & 63;
  const int wave = t >> 6;
  const int n0 = wave * 32;
  const int nl = lane & 15;
  const int quad = lane >> 4;

  bf16x8 bw[2][4];
#pragma unroll
  for (int nt = 0; nt < 2; ++nt)
#pragma unroll
    for (int kk = 0; kk < 4; ++kk)
      bw[nt][kk] = *(const bf16x8*)(W1t + (size_t)(n0 + nt * 16 + nl) * 128 + kk * 32 + quad * 8);

  f32x4 acc[8][2];
#pragma unroll
  for (int mt = 0; mt < 8; ++mt) {
    acc[mt][0] = (f32x4)0.0f;
    acc[mt][1] = (f32x4)0.0f;
  }
#pragma unroll
  for (int kk = 0; kk < 4; ++kk) {
#pragma unroll
    for (int mt = 0; mt < 8; ++mt) {
      bf16x8 a = *(const bf16x8*)(Xs + (mt * 16 + nl) * 136 + kk * 32 + quad * 8);
      acc[mt][0] = MFMA_BF16(a, bw[0][kk], acc[mt][0]);
      acc[mt][1] = MFMA_BF16(a, bw[1][kk], acc[mt][1]);
    }
  }
  __syncthreads();  // all GEMM1 A-reads complete before overwriting Xs with T
  // epilogue 1: bias + relu -> Xs (in place, bf16)
#pragma unroll
  for (int nt = 0; nt < 2; ++nt) {
    const int n = n0 + nt * 16 + nl;
    const float bias = b1[n];
#pragma unroll
    for (int mt = 0; mt < 8; ++mt)
#pragma unroll
      for (int r = 0; r < 4; ++r) {
        float v = acc[mt][nt][r] + bias;
        v = v > 0.f ? v : 0.f;
        Xs[(mt * 16 + quad * 4 + r) * 136 + n] = f2bf(v);
      }
  }
  __syncthreads();
  // GEMM2
#pragma unroll
  for (int nt = 0; nt < 2; ++nt)
#pragma unroll
    for (int kk = 0; kk < 4; ++kk)
      bw[nt][kk] = *(const bf16x8*)(W2t + (size_t)(n0 + nt * 16 + nl) * 128 + kk * 32 + quad * 8);
#pragma unroll
  for (int mt = 0; mt < 8; ++mt) {
    acc[mt][0] = (f32x4)0.0f;
    acc[mt][1] = (f32x4)0.0f;
  }
#pragma unroll
  for (int kk = 0; kk < 4; ++kk) {
#pragma unroll
    for (int mt = 0; mt < 8; ++mt) {
      bf16x8 a = *(const bf16x8*)(Xs + (mt * 16 + nl) * 136 + kk * 32 + quad * 8);
      acc[mt][0] = MFMA_BF16(a, bw[0][kk], acc[mt][0]);
      acc[mt][1] = MFMA_BF16(a, bw[1][kk], acc[mt][1]);
    }
  }
  // epilogue 2: bias, store Y (bf16), per-block BN partials (contention-free)
  float ssum[2] = {0.f, 0.f}, ssq[2] = {0.f, 0.f};
#pragma unroll
  for (int nt = 0; nt < 2; ++nt) {
    const int n = n0 + nt * 16 + nl;
    const float bias = b2[n];
#pragma unroll
    for (int mt = 0; mt < 8; ++mt)
#pragma unroll
      for (int r = 0; r < 4; ++r) {
        const int row = row0 + mt * 16 + quad * 4 + r;
        float v = acc[mt][nt][r] + bias;
        if (row < nrows) {
          Y[(size_t)row * 128 + n] = f2bf(v);
          ssum[nt] += v;
          ssq[nt] += v * v;
        }
      }
  }
#pragma unroll
  for (int nt = 0; nt < 2; ++nt) {
    float s = ssum[nt], q = ssq[nt];
    s += __shfl_xor(s, 16);
    q += __shfl_xor(q, 16);
    s += __shfl_xor(s, 32);
    q += __shfl_xor(q, 32);
    if (quad == 0) {
      const int n = n0 + nt * 16 + nl;
      part[(size_t)blockIdx.x * 256 + n] = s;
      part[(size_t)blockIdx.x * 256 + 128 + n] = q;
    }
  }
}

// ---- parallel column-reduce of PART + scale/shift compute, one dispatch.
// Block c: threads 0..127 sum column c (sums), 128..255 sum column 128+c (sumsq);
// LDS tree reduce; thread 0 writes scsh[c], scsh[128+c]. 128 blocks -> parallel
// (r7's ONE-block reduce ran at 7.5 GB/s and cost 106 us; this reads the same
// 0.8 MB L2-hot with 256x the parallelism).
__global__ __launch_bounds__(256) void bn_reduce_finalize(
    const float* __restrict__ part, int nblk, const float* __restrict__ g,
    const float* __restrict__ be, float invN, float* __restrict__ scsh) {
  __shared__ float red[2][128];
  const int c = blockIdx.x;  // 0..127
  const int t = threadIdx.x;
  const int half = t >> 7;
  const int tt = t & 127;
  const int col = c + half * 128;
  float s = 0.f;
  for (int b = tt; b < nblk; b += 128) s += part[(size_t)b * 256 + col];
  red[half][tt] = s;
  __syncthreads();
  for (int d = 64; d > 0; d >>= 1) {
    if (tt < d) red[half][tt] += red[half][tt + d];
    __syncthreads();
  }
  if (t == 0) {
    float mu = red[0][0] * invN;
    float var = red[1][0] * invN - mu * mu;
    float rstd = rsqrtf(var + 1e-5f);
    float sc = rstd * g[c];
    scsh[c] = sc;
    scsh[128 + c] = be[c] - mu * sc;
  }
}

// ---- pooling (fused layer-3 BN+relu via precomputed scsh) + final head, one block/graph
__global__ __launch_bounds__(256) void pool_final(
    const u16* __restrict__ Hh, const int* __restrict__ batch, const float* __restrict__ scsh,
    const float* __restrict__ f1w, const float* __restrict__ f1b, const float* __restrict__ f2w,
    const float* __restrict__ f2b, float* __restrict__ out, int nrows) {
  __shared__ float red[16][128];
  __shared__ float pr[128];
  __shared__ float tt[128];
  const int gid = blockIdx.x, t = threadIdx.x;
  int l = 0, r = nrows;
  while (l < r) {
    int m = (l + r) >> 1;
    if (batch[m] < gid) l = m + 1; else r = m;
  }
  const int s0 = l;
  r = nrows;
  while (l < r) {
    int m = (l + r) >> 1;
    if (batch[m] < gid + 1) l = m + 1; else r = m;
  }
  const int s1 = l;
  const int fl = t & 15;
  const int grp = t >> 4;
  float sc[8], sh[8];
#pragma unroll
  for (int i = 0; i < 8; ++i) {
    sc[i] = scsh[fl * 8 + i];
    sh[i] = scsh[128 + fl * 8 + i];
  }
  float a[8];
#pragma unroll
  for (int i = 0; i < 8; ++i) a[i] = 0.f;
  for (int i = s0 + grp; i < s1; i += 16) {
    uint4 v = *(const uint4*)(Hh + (size_t)i * 128 + fl * 8);
    const u16* pp = (const u16*)&v;
#pragma unroll
    for (int k = 0; k < 8; ++k) {
      float xv = bf2f(pp[k]) * sc[k] + sh[k];
      a[k] += xv > 0.f ? xv : 0.f;
    }
  }
#pragma unroll
  for (int k = 0; k < 8; ++k) red[grp][fl * 8 + k] = a[k];
  __syncthreads();
  if (t < 128) {
    float s = 0.f;
#pragma unroll
    for (int gg2 = 0; gg2 < 16; ++gg2) s += red[gg2][t];
    pr[t] = s;
  }
  __syncthreads();
  if (t < 128) {
    float s = f1b[t];
    for (int k = 0; k < 128; ++k) s += pr[k] * f1w[k * 128 + t];
    tt[t] = s > 0.f ? s : 0.f;
  }
  __syncthreads();
  if (t < 10) {
    float s2 = f2b[t];
    for (int k = 0; k < 128; ++k) s2 += tt[k] * f2w[k * 10 + t];
    out[gid * 10 + t] = s2;
  }
}

// ws layout (bytes):
//   H     @ 0          : 25,600,000  (bf16 node features)
//   AGG   @ 25,600,000 : 25,600,000  (bf16 aggregated, layer input tiles)
//   PAIRS @ 51,200,000 : 512*4608*4 = 9,437,184
//   CSR   @ 60,637,184 : 9,437,184
//   RS    @ 70,074,368 : 400,000
//   DEG   @ 70,474,368 : 400,000
//   CUR   @ 70,874,368 : 2,048       (zeroed)
//   SCSH  @ 70,876,416 : 3,072       (3 layers x 256 f32; written by bn_reduce_finalize)
//   WT    @ 70,879,488 : 196,608
//   TBL   @ 71,076,096 : 128,000
//   PART  @ 71,204,096 : 782*256*4 = 800,768 (per-block BN partials; fully overwritten)
extern "C" void kernel_launch(void* const* d_in, const int* in_sizes, int n_in, void* d_out,
                              int out_size, void* d_ws, size_t ws_size, hipStream_t stream) {
  const int* x = (const int*)d_in[0];
  const int* ei = (const int*)d_in[1];
  const int* batch = (const int*)d_in[2];
  const float* emb = (const float*)d_in[3];
  const float* iw1 = (const float*)d_in[4];
  const float* ib1 = (const float*)d_in[5];
  const float* iw2 = (const float*)d_in[6];
  const float* ib2 = (const float*)d_in[7];
  const float* f1w = (const float*)d_in[8];
  const float* f1b = (const float*)d_in[9];
  const float* f2w = (const float*)d_in[10];
  const float* f2b = (const float*)d_in[11];
  const float* cw1[3] = {(const float*)d_in[12], (const float*)d_in[18], (const float*)d_in[24]};
  const float* cb1[3] = {(const float*)d_in[13], (const float*)d_in[19], (const float*)d_in[25]};
  const float* cw2[3] = {(const float*)d_in[14], (const float*)d_in[20], (const float*)d_in[26]};
  const float* cb2[3] = {(const float*)d_in[15], (const float*)d_in[21], (const float*)d_in[27]};
  const float* gg[3] = {(const float*)d_in[16], (const float*)d_in[22], (const float*)d_in[28]};
  const float* bb[3] = {(const float*)d_in[17], (const float*)d_in[23], (const float*)d_in[29]};

  const int N_ = in_sizes[0];
  const int E_ = in_sizes[1] / 2;
  const int V_ = in_sizes[3] / 128;
  const int G_ = out_size / 10;
  const int NBUC = (N_ + 255) >> 8;
  const float invN = 1.0f / (float)N_;

  char* ws = (char*)d_ws;
  u16* H = (u16*)(ws + 0);
  u16* AGG = (u16*)(ws + 25600000);
  u32* PAIRS = (u32*)(ws + 51200000);
  u32* CSR = (u32*)(ws + 60637184);
  int* RS = (int*)(ws + 70074368);
  int* DEG = (int*)(ws + 70474368);
  u32* CUR = (u32*)(ws + 70874368);
  float* SCSH = (float*)(ws + 70876416);
  u16* WT = (u16*)(ws + 70879488);
  u16* TBL = (u16*)(ws + 71076096);
  float* PART = (float*)(ws + 71204096);

  hipMemsetAsync(ws + 70874368, 0, 2048, stream);  // CUR only

  prep_w6<<<384, 256, 0, stream>>>(cw1[0], cw2[0], cw1[1], cw2[1], cw1[2], cw2[2], WT);
  mlp0_table<<<V_, 128, 0, stream>>>(emb, iw1, ib1, iw2, ib2, TBL);
  bucket_scatter<<<(E_ + EPB - 1) / EPB, 256, 0, stream>>>(ei, ei + E_, PAIRS, CUR, E_, NBUC);
  csr_build<<<NBUC, 256, 0, stream>>>(PAIRS, CUR, CSR, RS, DEG, N_);

  const int ablk = (N_ + 3) / 4;
  const int mblk = (N_ + 127) / 128;
  for (int l = 0; l < 3; ++l) {
    const u16* W1 = WT + (size_t)l * 32768;
    const u16* W2 = WT + (size_t)l * 32768 + 16384;
    if (l == 0)
      agg_kernel<0><<<ablk, 256, 0, stream>>>(TBL, x, CSR, RS, DEG, nullptr, AGG, N_);
    else
      agg_kernel<1><<<ablk, 256, 0, stream>>>(H, nullptr, CSR, RS, DEG, SCSH + (l - 1) * 256,
                                              AGG, N_);
    mlp_kernel<<<mblk, 256, 0, stream>>>(AGG, W1, cb1[l], W2, cb2[l], H, PART, N_);
    bn_reduce_finalize<<<128, 256, 0, stream>>>(PART, mblk, gg[l], bb[l], invN,
                                                SCSH + l * 256);
  }
  pool_final<<<G_, 256, 0, stream>>>(H, batch, SCSH + 2 * 256, f1w, f1b, f2w, f2b,
                                     (float*)d_out, N_);
}

// Round 13
// 467.853 us; speedup vs baseline: 1.2194x; 1.0894x over previous
//
#include <hip/hip_runtime.h>

typedef unsigned short u16;
typedef unsigned int u32;
typedef __bf16 bf16x8 __attribute__((ext_vector_type(8)));
typedef float f32x4 __attribute__((ext_vector_type(4)));

#define MFMA_BF16(a, b, c) __builtin_amdgcn_mfma_f32_16x16x32_bf16(a, b, c, 0, 0, 0)

#define NBUC_MAX 512
#define BCAP 4608
#define EPB 2048  // edges per block in bucket_scatter (r12: 782 blocks = 3/CU)

__device__ __forceinline__ float bf2f(u16 h) {
  u32 u = ((u32)h) << 16;
  return __builtin_bit_cast(float, u);
}
__device__ __forceinline__ u16 f2bf(float f) {
  u32 u = __builtin_bit_cast(u32, f);
  u += 0x7fffu + ((u >> 16) & 1u);
  return (u16)(u >> 16);
}

// ---- weight prep: 6 conv weights fp32 [k][n] -> bf16 transposed [n][k], one dispatch
__global__ __launch_bounds__(256) void prep_w6(const float* __restrict__ w0,
                                               const float* __restrict__ w1,
                                               const float* __restrict__ w2,
                                               const float* __restrict__ w3,
                                               const float* __restrict__ w4,
                                               const float* __restrict__ w5,
                                               u16* __restrict__ wt) {
  const int which = blockIdx.x >> 6;
  const float* w = which == 0 ? w0 : which == 1 ? w1 : which == 2 ? w2
                  : which == 3 ? w3 : which == 4 ? w4 : w5;
  int t = (blockIdx.x & 63) * 256 + threadIdx.x;  // 16384 elems per matrix
  int n = t >> 7, k = t & 127;
  wt[which * 16384 + n * 128 + k] = f2bf(w[k * 128 + n]);
}

// ---- initial MLP applied to the 500-row embedding table (h0 = table2[x])
__global__ __launch_bounds__(128) void mlp0_table(
    const float* __restrict__ emb, const float* __restrict__ w1, const float* __restrict__ b1,
    const float* __restrict__ w2, const float* __restrict__ b2, u16* __restrict__ table) {
  __shared__ float e[128];
  __shared__ float tt[128];
  int r = blockIdx.x, j = threadIdx.x;
  e[j] = emb[r * 128 + j];
  __syncthreads();
  float s = b1[j];
  for (int k = 0; k < 128; ++k) s += e[k] * w1[k * 128 + j];
  tt[j] = s > 0.f ? s : 0.f;
  __syncthreads();
  float s2 = b2[j];
  for (int k = 0; k < 128; ++k) s2 += tt[k] * w2[k * 128 + j];
  table[r * 128 + j] = f2bf(s2);
}

// ---- pass 1: bucket edges by dst>>8, packed (src<<8)|dloc. No LDS staging; LDS = 4 KB.
__global__ __launch_bounds__(256) void bucket_scatter(const int* __restrict__ src,
                                                      const int* __restrict__ dst,
                                                      u32* __restrict__ pairs,
                                                      u32* __restrict__ cursor, int E_, int nbuc) {
  __shared__ u32 lcnt[NBUC_MAX];
  __shared__ u32 lbase[NBUC_MAX];
  const int t = threadIdx.x;
  for (int b = t; b < NBUC_MAX; b += 256) lcnt[b] = 0;
  __syncthreads();
  const int e0 = blockIdx.x * EPB;
#pragma unroll
  for (int it = 0; it < EPB / 256; ++it) {
    int e = e0 + it * 256 + t;
    if (e < E_) atomicAdd(&lcnt[((u32)dst[e]) >> 8], 1u);
  }
  __syncthreads();
  for (int b = t; b < nbuc; b += 256) {
    u32 c = lcnt[b];
    lbase[b] = c ? atomicAdd(&cursor[b], c) : 0u;
    lcnt[b] = 0;
  }
  __syncthreads();
#pragma unroll
  for (int it = 0; it < EPB / 256; ++it) {
    int e = e0 + it * 256 + t;
    if (e < E_) {
      int d = dst[e];
      u32 b = ((u32)d) >> 8;
      u32 r = atomicAdd(&lcnt[b], 1u);
      u32 p = lbase[b] + r;
      if (p < BCAP) pairs[(size_t)b * BCAP + p] = (((u32)src[e]) << 8) | (u32)(d & 255);
    }
  }
}

// ---- pass 2: per-bucket exact CSR (256 nodes/bucket): LDS count + scan + rank scatter
__global__ __launch_bounds__(256) void csr_build(const u32* __restrict__ pairs,
                                                 const u32* __restrict__ cursor,
                                                 u32* __restrict__ csr, int* __restrict__ RS,
                                                 int* __restrict__ DEG, int nrows) {
  __shared__ u32 cnt[256];
  __shared__ u32 offs[256];
  __shared__ u32 basearr[256];
  const int b = blockIdx.x, t = threadIdx.x;
  u32 count = cursor[b];
  if (count > BCAP) count = BCAP;
  cnt[t] = 0;
  __syncthreads();
  const u32* pb = pairs + (size_t)b * BCAP;
  for (u32 i = t; i < count; i += 256) atomicAdd(&cnt[pb[i] & 255u], 1u);
  __syncthreads();
  const u32 my = cnt[t];
  offs[t] = my;
  __syncthreads();
  for (int d = 1; d < 256; d <<= 1) {
    u32 v = (t >= d) ? offs[t - d] : 0u;
    __syncthreads();
    offs[t] += v;
    __syncthreads();
  }
  const u32 excl = offs[t] - my;  // exclusive prefix
  const int node = (b << 8) + t;
  if (node < nrows) {
    RS[node] = b * BCAP + (int)excl;
    DEG[node] = (int)my;
  }
  basearr[t] = excl;
  cnt[t] = 0;
  __syncthreads();
  for (u32 i = t; i < count; i += 256) {
    u32 v = pb[i];
    u32 dl = v & 255u;
    u32 r = atomicAdd(&cnt[dl], 1u);
    csr[(size_t)b * BCAP + basearr[dl] + r] = v >> 8;
  }
}

// ---- aggregation (exact r8/r11/r12 config — 69-70 us, VALU 65% = its VALU floor):
// AGG[i] = f(row(i)) + sum_j f(row(j)).  MODE 0: row(i)=TBL[x[i]], f=id.
// MODE 1: row(i)=H[i], f=BN-affine+relu (scsh precomputed).  Fused per-edge BN is
// net-cheaper than a separate pass (r9). Scalar f32 math (r10 packed regressed).
// 2-deep pipeline (r6: wider predication regresses). 32-bit byte offsets.
template <int MODE>
__global__ __launch_bounds__(256) void agg_kernel(
    const u16* __restrict__ Hsrc, const int* __restrict__ x, const u32* __restrict__ csr,
    const int* __restrict__ RS, const int* __restrict__ DEG, const float* __restrict__ scsh,
    u16* __restrict__ AGG, int nrows) {
  int node = blockIdx.x * 4 + (threadIdx.x >> 6);
  if (node >= nrows) return;
  const int lane = threadIdx.x & 63;
  const int grp = lane >> 4;  // neighbor sub-slot 0..3
  const int fl = lane & 15;   // 16B feature chunk
  const int deg = DEG[node];
  const u32* cl = csr + RS[node];
  const char* Hb = (const char*)Hsrc;
  const u32 flo = (u32)fl << 4;

  float sc[8], sh[8];
  if (MODE == 1) {
#pragma unroll
    for (int i = 0; i < 8; ++i) {
      sc[i] = scsh[fl * 8 + i];
      sh[i] = scsh[128 + fl * 8 + i];
    }
  }
  float a[8];
#pragma unroll
  for (int i = 0; i < 8; ++i) a[i] = 0.f;

#define ACCUM(vv)                                   \
  {                                                 \
    const u16* p = (const u16*)&(vv);               \
    _Pragma("unroll") for (int i = 0; i < 8; ++i) { \
      float xv = bf2f(p[i]);                        \
      if (MODE == 1) {                              \
        xv = xv * sc[i] + sh[i];                    \
        xv = xv > 0.f ? xv : 0.f;                   \
      }                                             \
      a[i] += xv;                                   \
    }                                               \
  }
#define ROWOFF(idx) ((((u32)(MODE == 0 ? x[(idx)] : (idx))) << 8) + flo)

  if (grp == 0) {
    uint4 v = *(const uint4*)(Hb + ROWOFF(node));
    ACCUM(v);
  }
  int j = grp;
  int cA = (j < deg) ? (int)cl[j] : 0;
  int cB = (j + 4 < deg) ? (int)cl[j + 4] : 0;
  uint4 nv = make_uint4(0u, 0u, 0u, 0u);
  if (j < deg) nv = *(const uint4*)(Hb + ROWOFF(cA));
  while (j < deg) {
    uint4 cv = nv;
    int cn = cB;
    cB = (j + 8 < deg) ? (int)cl[j + 8] : 0;
    if (j + 4 < deg) nv = *(const uint4*)(Hb + ROWOFF(cn));
    ACCUM(cv);
    j += 4;
  }
#undef ROWOFF
#undef ACCUM

#pragma unroll
  for (int i = 0; i < 8; ++i) {
    a[i] += __shfl_xor(a[i], 16);
    a[i] += __shfl_xor(a[i], 32);
  }
  if (grp == 0) {
    u32 o[4];
#pragma unroll
    for (int i = 0; i < 4; ++i) o[i] = (u32)f2bf(a[2 * i]) | ((u32)f2bf(a[2 * i + 1]) << 16);
    *(uint4*)(AGG + (size_t)node * 128 + fl * 8) = *(uint4*)o;
  }
}

// ---- fused 2-layer MLP (bf16 MFMA), 128-row x 128-col tile, 4 waves, T in-place.
// C-write now routed through Xs: r12's epilogue stored Y as 64 scalar
// global_store_short per thread (column-major fragment -> non-coalescible 2B
// stores, 16k store insts/block). Now: C -> Xs (bf16, LDS), barrier, then the
// SAME coalesced uint4 pattern as the staging load (8 x 16B per thread).
// BN stats -> PART[block][256] plain stores (r12: atomic tail was ~14-28 us/layer).
__global__ __launch_bounds__(256) void mlp_kernel(
    const u16* __restrict__ X, const u16* __restrict__ W1t, const float* __restrict__ b1,
    const u16* __restrict__ W2t, const float* __restrict__ b2, u16* __restrict__ Y,
    float* __restrict__ part, int nrows) {
  __shared__ u16 Xs[128 * 136];
  const int t = threadIdx.x;
  const int row0 = blockIdx.x * 128;
  {
    const int seg = t & 15;
    const int rb = t >> 4;
#pragma unroll
    for (int p = 0; p < 8; ++p) {
      const int r = rb + p * 16;
      const int gr = row0 + r;
      uint4 v = make_uint4(0u, 0u, 0u, 0u);
      if (gr < nrows) v = *(const uint4*)(X + (size_t)gr * 128 + seg * 8);
      *(uint4*)(Xs + r * 136 + seg * 8) = v;
    }
  }
  __syncthreads();
  const int lane = t & 63;
  const int wave = t >> 6;
  const int n0 = wave * 32;
  const int nl = lane & 15;
  const int quad = lane >> 4;

  bf16x8 bw[2][4];
#pragma unroll
  for (int nt = 0; nt < 2; ++nt)
#pragma unroll
    for (int kk = 0; kk < 4; ++kk)
      bw[nt][kk] = *(const bf16x8*)(W1t + (size_t)(n0 + nt * 16 + nl) * 128 + kk * 32 + quad * 8);

  f32x4 acc[8][2];
#pragma unroll
  for (int mt = 0; mt < 8; ++mt) {
    acc[mt][0] = (f32x4)0.0f;
    acc[mt][1] = (f32x4)0.0f;
  }
#pragma unroll
  for (int kk = 0; kk < 4; ++kk) {
#pragma unroll
    for (int mt = 0; mt < 8; ++mt) {
      bf16x8 a = *(const bf16x8*)(Xs + (mt * 16 + nl) * 136 + kk * 32 + quad * 8);
      acc[mt][0] = MFMA_BF16(a, bw[0][kk], acc[mt][0]);
      acc[mt][1] = MFMA_BF16(a, bw[1][kk], acc[mt][1]);
    }
  }
  __syncthreads();  // all GEMM1 A-reads complete before overwriting Xs with T
  // epilogue 1: bias + relu -> Xs (in place, bf16)
#pragma unroll
  for (int nt = 0; nt < 2; ++nt) {
    const int n = n0 + nt * 16 + nl;
    const float bias = b1[n];
#pragma unroll
    for (int mt = 0; mt < 8; ++mt)
#pragma unroll
      for (int r = 0; r < 4; ++r) {
        float v = acc[mt][nt][r] + bias;
        v = v > 0.f ? v : 0.f;
        Xs[(mt * 16 + quad * 4 + r) * 136 + n] = f2bf(v);
      }
  }
  __syncthreads();
  // GEMM2
#pragma unroll
  for (int nt = 0; nt < 2; ++nt)
#pragma unroll
    for (int kk = 0; kk < 4; ++kk)
      bw[nt][kk] = *(const bf16x8*)(W2t + (size_t)(n0 + nt * 16 + nl) * 128 + kk * 32 + quad * 8);
#pragma unroll
  for (int mt = 0; mt < 8; ++mt) {
    acc[mt][0] = (f32x4)0.0f;
    acc[mt][1] = (f32x4)0.0f;
  }
#pragma unroll
  for (int kk = 0; kk < 4; ++kk) {
#pragma unroll
    for (int mt = 0; mt < 8; ++mt) {
      bf16x8 a = *(const bf16x8*)(Xs + (mt * 16 + nl) * 136 + kk * 32 + quad * 8);
      acc[mt][0] = MFMA_BF16(a, bw[0][kk], acc[mt][0]);
      acc[mt][1] = MFMA_BF16(a, bw[1][kk], acc[mt][1]);
    }
  }
  __syncthreads();  // all GEMM2 A-reads complete before overwriting Xs with C
  // epilogue 2: bias; BN partials from registers; C -> Xs (bf16)
  float ssum[2] = {0.f, 0.f}, ssq[2] = {0.f, 0.f};
#pragma unroll
  for (int nt = 0; nt < 2; ++nt) {
    const int n = n0 + nt * 16 + nl;
    const float bias = b2[n];
#pragma unroll
    for (int mt = 0; mt < 8; ++mt)
#pragma unroll
      for (int r = 0; r < 4; ++r) {
        const int row = row0 + mt * 16 + quad * 4 + r;
        float v = acc[mt][nt][r] + bias;
        if (row < nrows) {
          ssum[nt] += v;
          ssq[nt] += v * v;
        }
        Xs[(mt * 16 + quad * 4 + r) * 136 + n] = f2bf(v);
      }
  }
#pragma unroll
  for (int nt = 0; nt < 2; ++nt) {
    float s = ssum[nt], q = ssq[nt];
    s += __shfl_xor(s, 16);
    q += __shfl_xor(q, 16);
    s += __shfl_xor(s, 32);
    q += __shfl_xor(q, 32);
    if (quad == 0) {
      const int n = n0 + nt * 16 + nl;
      part[(size_t)blockIdx.x * 256 + n] = s;
      part[(size_t)blockIdx.x * 256 + 128 + n] = q;
    }
  }
  __syncthreads();
  // coalesced Y store (same pattern as staging load)
  {
    const int seg = t & 15;
    const int rb = t >> 4;
#pragma unroll
    for (int p = 0; p < 8; ++p) {
      const int r = rb + p * 16;
      const int gr = row0 + r;
      if (gr < nrows)
        *(uint4*)(Y + (size_t)gr * 128 + seg * 8) = *(const uint4*)(Xs + r * 136 + seg * 8);
    }
  }
}

// ---- parallel column-reduce of PART + scale/shift compute (r12-proven, ~free)
__global__ __launch_bounds__(256) void bn_reduce_finalize(
    const float* __restrict__ part, int nblk, const float* __restrict__ g,
    const float* __restrict__ be, float invN, float* __restrict__ scsh) {
  __shared__ float red[2][128];
  const int c = blockIdx.x;  // 0..127
  const int t = threadIdx.x;
  const int half = t >> 7;
  const int tt = t & 127;
  const int col = c + half * 128;
  float s = 0.f;
  for (int b = tt; b < nblk; b += 128) s += part[(size_t)b * 256 + col];
  red[half][tt] = s;
  __syncthreads();
  for (int d = 64; d > 0; d >>= 1) {
    if (tt < d) red[half][tt] += red[half][tt + d];
    __syncthreads();
  }
  if (t == 0) {
    float mu = red[0][0] * invN;
    float var = red[1][0] * invN - mu * mu;
    float rstd = rsqrtf(var + 1e-5f);
    float sc = rstd * g[c];
    scsh[c] = sc;
    scsh[128 + c] = be[c] - mu * sc;
  }
}

// ---- pooling (fused layer-3 BN+relu via precomputed scsh) + final head, one block/graph
__global__ __launch_bounds__(256) void pool_final(
    const u16* __restrict__ Hh, const int* __restrict__ batch, const float* __restrict__ scsh,
    const float* __restrict__ f1w, const float* __restrict__ f1b, const float* __restrict__ f2w,
    const float* __restrict__ f2b, float* __restrict__ out, int nrows) {
  __shared__ float red[16][128];
  __shared__ float pr[128];
  __shared__ float tt[128];
  const int gid = blockIdx.x, t = threadIdx.x;
  int l = 0, r = nrows;
  while (l < r) {
    int m = (l + r) >> 1;
    if (batch[m] < gid) l = m + 1; else r = m;
  }
  const int s0 = l;
  r = nrows;
  while (l < r) {
    int m = (l + r) >> 1;
    if (batch[m] < gid + 1) l = m + 1; else r = m;
  }
  const int s1 = l;
  const int fl = t & 15;
  const int grp = t >> 4;
  float sc[8], sh[8];
#pragma unroll
  for (int i = 0; i < 8; ++i) {
    sc[i] = scsh[fl * 8 + i];
    sh[i] = scsh[128 + fl * 8 + i];
  }
  float a[8];
#pragma unroll
  for (int i = 0; i < 8; ++i) a[i] = 0.f;
  for (int i = s0 + grp; i < s1; i += 16) {
    uint4 v = *(const uint4*)(Hh + (size_t)i * 128 + fl * 8);
    const u16* pp = (const u16*)&v;
#pragma unroll
    for (int k = 0; k < 8; ++k) {
      float xv = bf2f(pp[k]) * sc[k] + sh[k];
      a[k] += xv > 0.f ? xv : 0.f;
    }
  }
#pragma unroll
  for (int k = 0; k < 8; ++k) red[grp][fl * 8 + k] = a[k];
  __syncthreads();
  if (t < 128) {
    float s = 0.f;
#pragma unroll
    for (int gg2 = 0; gg2 < 16; ++gg2) s += red[gg2][t];
    pr[t] = s;
  }
  __syncthreads();
  if (t < 128) {
    float s = f1b[t];
    for (int k = 0; k < 128; ++k) s += pr[k] * f1w[k * 128 + t];
    tt[t] = s > 0.f ? s : 0.f;
  }
  __syncthreads();
  if (t < 10) {
    float s2 = f2b[t];
    for (int k = 0; k < 128; ++k) s2 += tt[k] * f2w[k * 10 + t];
    out[gid * 10 + t] = s2;
  }
}

// ws layout (bytes):
//   H     @ 0          : 25,600,000  (bf16 node features)
//   AGG   @ 25,600,000 : 25,600,000  (bf16 aggregated, layer input tiles)
//   PAIRS @ 51,200,000 : 512*4608*4 = 9,437,184
//   CSR   @ 60,637,184 : 9,437,184
//   RS    @ 70,074,368 : 400,000
//   DEG   @ 70,474,368 : 400,000
//   CUR   @ 70,874,368 : 2,048       (zeroed)
//   SCSH  @ 70,876,416 : 3,072       (3 layers x 256 f32; written by bn_reduce_finalize)
//   WT    @ 70,879,488 : 196,608
//   TBL   @ 71,076,096 : 128,000
//   PART  @ 71,204,096 : 782*256*4 = 800,768 (per-block BN partials; fully overwritten)
extern "C" void kernel_launch(void* const* d_in, const int* in_sizes, int n_in, void* d_out,
                              int out_size, void* d_ws, size_t ws_size, hipStream_t stream) {
  const int* x = (const int*)d_in[0];
  const int* ei = (const int*)d_in[1];
  const int* batch = (const int*)d_in[2];
  const float* emb = (const float*)d_in[3];
  const float* iw1 = (const float*)d_in[4];
  const float* ib1 = (const float*)d_in[5];
  const float* iw2 = (const float*)d_in[6];
  const float* ib2 = (const float*)d_in[7];
  const float* f1w = (const float*)d_in[8];
  const float* f1b = (const float*)d_in[9];
  const float* f2w = (const float*)d_in[10];
  const float* f2b = (const float*)d_in[11];
  const float* cw1[3] = {(const float*)d_in[12], (const float*)d_in[18], (const float*)d_in[24]};
  const float* cb1[3] = {(const float*)d_in[13], (const float*)d_in[19], (const float*)d_in[25]};
  const float* cw2[3] = {(const float*)d_in[14], (const float*)d_in[20], (const float*)d_in[26]};
  const float* cb2[3] = {(const float*)d_in[15], (const float*)d_in[21], (const float*)d_in[27]};
  const float* gg[3] = {(const float*)d_in[16], (const float*)d_in[22], (const float*)d_in[28]};
  const float* bb[3] = {(const float*)d_in[17], (const float*)d_in[23], (const float*)d_in[29]};

  const int N_ = in_sizes[0];
  const int E_ = in_sizes[1] / 2;
  const int V_ = in_sizes[3] / 128;
  const int G_ = out_size / 10;
  const int NBUC = (N_ + 255) >> 8;
  const float invN = 1.0f / (float)N_;

  char* ws = (char*)d_ws;
  u16* H = (u16*)(ws + 0);
  u16* AGG = (u16*)(ws + 25600000);
  u32* PAIRS = (u32*)(ws + 51200000);
  u32* CSR = (u32*)(ws + 60637184);
  int* RS = (int*)(ws + 70074368);
  int* DEG = (int*)(ws + 70474368);
  u32* CUR = (u32*)(ws + 70874368);
  float* SCSH = (float*)(ws + 70876416);
  u16* WT = (u16*)(ws + 70879488);
  u16* TBL = (u16*)(ws + 71076096);
  float* PART = (float*)(ws + 71204096);

  hipMemsetAsync(ws + 70874368, 0, 2048, stream);  // CUR only

  prep_w6<<<384, 256, 0, stream>>>(cw1[0], cw2[0], cw1[1], cw2[1], cw1[2], cw2[2], WT);
  mlp0_table<<<V_, 128, 0, stream>>>(emb, iw1, ib1, iw2, ib2, TBL);
  bucket_scatter<<<(E_ + EPB - 1) / EPB, 256, 0, stream>>>(ei, ei + E_, PAIRS, CUR, E_, NBUC);
  csr_build<<<NBUC, 256, 0, stream>>>(PAIRS, CUR, CSR, RS, DEG, N_);

  const int ablk = (N_ + 3) / 4;
  const int mblk = (N_ + 127) / 128;
  for (int l = 0; l < 3; ++l) {
    const u16* W1 = WT + (size_t)l * 32768;
    const u16* W2 = WT + (size_t)l * 32768 + 16384;
    if (l == 0)
      agg_kernel<0><<<ablk, 256, 0, stream>>>(TBL, x, CSR, RS, DEG, nullptr, AGG, N_);
    else
      agg_kernel<1><<<ablk, 256, 0, stream>>>(H, nullptr, CSR, RS, DEG, SCSH + (l - 1) * 256,
                                              AGG, N_);
    mlp_kernel<<<mblk, 256, 0, stream>>>(AGG, W1, cb1[l], W2, cb2[l], H, PART, N_);
    bn_reduce_finalize<<<128, 256, 0, stream>>>(PART, mblk, gg[l], bb[l], invN,
                                                SCSH + l * 256);
  }
  pool_final<<<G_, 256, 0, stream>>>(H, batch, SCSH + 2 * 256, f1w, f1b, f2w, f2b,
                                     (float*)d_out, N_);
}

// Round 14
// 465.864 us; speedup vs baseline: 1.2246x; 1.0043x over previous
//
#include <hip/hip_runtime.h>

typedef unsigned short u16;
typedef unsigned int u32;
typedef __bf16 bf16x8 __attribute__((ext_vector_type(8)));
typedef float f32x4 __attribute__((ext_vector_type(4)));
typedef float f32x2a __attribute__((ext_vector_type(2)));

#define MFMA_BF16(a, b, c) __builtin_amdgcn_mfma_f32_16x16x32_bf16(a, b, c, 0, 0, 0)

#define NBUC_MAX 512
#define BCAP 4608
#define EPB 2048  // edges per block in bucket_scatter (782 blocks = 3/CU)

__device__ __forceinline__ float bf2f(u16 h) {
  u32 u = ((u32)h) << 16;
  return __builtin_bit_cast(float, u);
}
__device__ __forceinline__ u16 f2bf_sw(float f) {
  u32 u = __builtin_bit_cast(u32, f);
  u += 0x7fffu + ((u >> 16) & 1u);
  return (u16)(u >> 16);
}
// packed f32x2 -> bf16x2 (u32). HW v_cvt_pk_bf16_f32 on gfx950 (1 inst vs ~9 sw).
#if __has_builtin(__builtin_amdgcn_cvt_pk_bf16_f32)
__device__ __forceinline__ u32 f2bf_pk(float a, float b) {
  auto r = __builtin_amdgcn_cvt_pk_bf16_f32(a, b);
  return __builtin_bit_cast(u32, r);
}
#else
__device__ __forceinline__ u32 f2bf_pk(float a, float b) {
  return (u32)f2bf_sw(a) | ((u32)f2bf_sw(b) << 16);
}
#endif
__device__ __forceinline__ u16 f2bf(float f) { return (u16)f2bf_pk(f, f); }

// forced VOP3P packed math (r10: compiler won't lower generic vectors to v_pk_*;
// inline asm guarantees it — CK-style constraints)
__device__ __forceinline__ f32x2a pk_fma2(f32x2a a, f32x2a b, f32x2a c) {
  f32x2a d;
  asm volatile("v_pk_fma_f32 %0, %1, %2, %3" : "=v"(d) : "v"(a), "v"(b), "v"(c));
  return d;
}
__device__ __forceinline__ f32x2a pk_add2(f32x2a a, f32x2a b) {
  f32x2a d;
  asm volatile("v_pk_add_f32 %0, %1, %2" : "=v"(d) : "v"(a), "v"(b));
  return d;
}

// ---- weight prep: 6 conv weights fp32 [k][n] -> bf16 transposed [n][k], one dispatch
__global__ __launch_bounds__(256) void prep_w6(const float* __restrict__ w0,
                                               const float* __restrict__ w1,
                                               const float* __restrict__ w2,
                                               const float* __restrict__ w3,
                                               const float* __restrict__ w4,
                                               const float* __restrict__ w5,
                                               u16* __restrict__ wt) {
  const int which = blockIdx.x >> 6;
  const float* w = which == 0 ? w0 : which == 1 ? w1 : which == 2 ? w2
                  : which == 3 ? w3 : which == 4 ? w4 : w5;
  int t = (blockIdx.x & 63) * 256 + threadIdx.x;  // 16384 elems per matrix
  int n = t >> 7, k = t & 127;
  wt[which * 16384 + n * 128 + k] = f2bf(w[k * 128 + n]);
}

// ---- initial MLP applied to the 500-row embedding table (h0 = table2[x])
__global__ __launch_bounds__(128) void mlp0_table(
    const float* __restrict__ emb, const float* __restrict__ w1, const float* __restrict__ b1,
    const float* __restrict__ w2, const float* __restrict__ b2, u16* __restrict__ table) {
  __shared__ float e[128];
  __shared__ float tt[128];
  int r = blockIdx.x, j = threadIdx.x;
  e[j] = emb[r * 128 + j];
  __syncthreads();
  float s = b1[j];
  for (int k = 0; k < 128; ++k) s += e[k] * w1[k * 128 + j];
  tt[j] = s > 0.f ? s : 0.f;
  __syncthreads();
  float s2 = b2[j];
  for (int k = 0; k < 128; ++k) s2 += tt[k] * w2[k * 128 + j];
  table[r * 128 + j] = f2bf(s2);
}

// ---- pass 1: bucket edges by dst>>8, packed (src<<8)|dloc. No LDS staging; LDS = 4 KB.
__global__ __launch_bounds__(256) void bucket_scatter(const int* __restrict__ src,
                                                      const int* __restrict__ dst,
                                                      u32* __restrict__ pairs,
                                                      u32* __restrict__ cursor, int E_, int nbuc) {
  __shared__ u32 lcnt[NBUC_MAX];
  __shared__ u32 lbase[NBUC_MAX];
  const int t = threadIdx.x;
  for (int b = t; b < NBUC_MAX; b += 256) lcnt[b] = 0;
  __syncthreads();
  const int e0 = blockIdx.x * EPB;
#pragma unroll
  for (int it = 0; it < EPB / 256; ++it) {
    int e = e0 + it * 256 + t;
    if (e < E_) atomicAdd(&lcnt[((u32)dst[e]) >> 8], 1u);
  }
  __syncthreads();
  for (int b = t; b < nbuc; b += 256) {
    u32 c = lcnt[b];
    lbase[b] = c ? atomicAdd(&cursor[b], c) : 0u;
    lcnt[b] = 0;
  }
  __syncthreads();
#pragma unroll
  for (int it = 0; it < EPB / 256; ++it) {
    int e = e0 + it * 256 + t;
    if (e < E_) {
      int d = dst[e];
      u32 b = ((u32)d) >> 8;
      u32 r = atomicAdd(&lcnt[b], 1u);
      u32 p = lbase[b] + r;
      if (p < BCAP) pairs[(size_t)b * BCAP + p] = (((u32)src[e]) << 8) | (u32)(d & 255);
    }
  }
}

// ---- pass 2: per-bucket exact CSR (256 nodes/bucket): LDS count + scan + rank scatter
__global__ __launch_bounds__(256) void csr_build(const u32* __restrict__ pairs,
                                                 const u32* __restrict__ cursor,
                                                 u32* __restrict__ csr, int* __restrict__ RS,
                                                 int* __restrict__ DEG, int nrows) {
  __shared__ u32 cnt[256];
  __shared__ u32 offs[256];
  __shared__ u32 basearr[256];
  const int b = blockIdx.x, t = threadIdx.x;
  u32 count = cursor[b];
  if (count > BCAP) count = BCAP;
  cnt[t] = 0;
  __syncthreads();
  const u32* pb = pairs + (size_t)b * BCAP;
  for (u32 i = t; i < count; i += 256) atomicAdd(&cnt[pb[i] & 255u], 1u);
  __syncthreads();
  const u32 my = cnt[t];
  offs[t] = my;
  __syncthreads();
  for (int d = 1; d < 256; d <<= 1) {
    u32 v = (t >= d) ? offs[t - d] : 0u;
    __syncthreads();
    offs[t] += v;
    __syncthreads();
  }
  const u32 excl = offs[t] - my;  // exclusive prefix
  const int node = (b << 8) + t;
  if (node < nrows) {
    RS[node] = b * BCAP + (int)excl;
    DEG[node] = (int)my;
  }
  basearr[t] = excl;
  cnt[t] = 0;
  __syncthreads();
  for (u32 i = t; i < count; i += 256) {
    u32 v = pb[i];
    u32 dl = v & 255u;
    u32 r = atomicAdd(&cnt[dl], 1u);
    csr[(size_t)b * BCAP + basearr[dl] + r] = v >> 8;
  }
}

// ---- aggregation: AGG[i] = f(row(i)) + sum_j f(row(j)).
// MODE 0: row(i)=TBL[x[i]], f=id.  MODE 1: row(i)=H[i], f=BN-affine+relu (scsh
// precomputed). Fused per-edge BN (r9: separate pass nets worse). Structure = r13
// (2-deep pipeline, 32-bit byte offsets). NEW: ACCUM via forced v_pk_fma/add_f32
// (MODE1 8->6 insts/pair, MODE0 4->3); output via v_cvt_pk_bf16_f32.
template <int MODE>
__global__ __launch_bounds__(256) void agg_kernel(
    const u16* __restrict__ Hsrc, const int* __restrict__ x, const u32* __restrict__ csr,
    const int* __restrict__ RS, const int* __restrict__ DEG, const float* __restrict__ scsh,
    u16* __restrict__ AGG, int nrows) {
  int node = blockIdx.x * 4 + (threadIdx.x >> 6);
  if (node >= nrows) return;
  const int lane = threadIdx.x & 63;
  const int grp = lane >> 4;  // neighbor sub-slot 0..3
  const int fl = lane & 15;   // 16B feature chunk
  const int deg = DEG[node];
  const u32* cl = csr + RS[node];
  const char* Hb = (const char*)Hsrc;
  const u32 flo = (u32)fl << 4;

  f32x2a sc2[4], sh2[4];
  if (MODE == 1) {
#pragma unroll
    for (int i = 0; i < 4; ++i) {
      sc2[i].x = scsh[fl * 8 + 2 * i];
      sc2[i].y = scsh[fl * 8 + 2 * i + 1];
      sh2[i].x = scsh[128 + fl * 8 + 2 * i];
      sh2[i].y = scsh[128 + fl * 8 + 2 * i + 1];
    }
  }
  f32x2a a2[4];
#pragma unroll
  for (int i = 0; i < 4; ++i) a2[i] = (f32x2a)0.f;

#define ACCUM(vv)                                        \
  {                                                      \
    const u32* q = (const u32*)&(vv);                    \
    _Pragma("unroll") for (int i = 0; i < 4; ++i) {      \
      u32 u = q[i];                                      \
      f32x2a xv;                                         \
      xv.x = __builtin_bit_cast(float, u << 16);         \
      xv.y = __builtin_bit_cast(float, u & 0xffff0000u); \
      if (MODE == 1) {                                   \
        xv = pk_fma2(xv, sc2[i], sh2[i]);                \
        xv.x = xv.x > 0.f ? xv.x : 0.f;                  \
        xv.y = xv.y > 0.f ? xv.y : 0.f;                  \
      }                                                  \
      a2[i] = pk_add2(a2[i], xv);                        \
    }                                                    \
  }
#define ROWOFF(idx) ((((u32)(MODE == 0 ? x[(idx)] : (idx))) << 8) + flo)

  if (grp == 0) {
    uint4 v = *(const uint4*)(Hb + ROWOFF(node));
    ACCUM(v);
  }
  int j = grp;
  int cA = (j < deg) ? (int)cl[j] : 0;
  int cB = (j + 4 < deg) ? (int)cl[j + 4] : 0;
  uint4 nv = make_uint4(0u, 0u, 0u, 0u);
  if (j < deg) nv = *(const uint4*)(Hb + ROWOFF(cA));
  while (j < deg) {
    uint4 cv = nv;
    int cn = cB;
    cB = (j + 8 < deg) ? (int)cl[j + 8] : 0;
    if (j + 4 < deg) nv = *(const uint4*)(Hb + ROWOFF(cn));
    ACCUM(cv);
    j += 4;
  }
#undef ROWOFF
#undef ACCUM

#pragma unroll
  for (int i = 0; i < 4; ++i) {
    a2[i].x += __shfl_xor(a2[i].x, 16);
    a2[i].y += __shfl_xor(a2[i].y, 16);
    a2[i].x += __shfl_xor(a2[i].x, 32);
    a2[i].y += __shfl_xor(a2[i].y, 32);
  }
  if (grp == 0) {
    u32 o[4];
#pragma unroll
    for (int i = 0; i < 4; ++i) o[i] = f2bf_pk(a2[i].x, a2[i].y);
    *(uint4*)(AGG + (size_t)node * 128 + fl * 8) = *(uint4*)o;
  }
}

// ---- fused 2-layer MLP (bf16 MFMA), 128-row x 128-col tile, 4 waves, T in-place,
// C routed through Xs then coalesced uint4 store (r13). Epilogue conversions now
// v_cvt_pk_bf16_f32 (128 sw f2bf/thread was ~770 cyc). BN stats -> PART (r12).
__global__ __launch_bounds__(256) void mlp_kernel(
    const u16* __restrict__ X, const u16* __restrict__ W1t, const float* __restrict__ b1,
    const u16* __restrict__ W2t, const float* __restrict__ b2, u16* __restrict__ Y,
    float* __restrict__ part, int nrows) {
  __shared__ u16 Xs[128 * 136];
  const int t = threadIdx.x;
  const int row0 = blockIdx.x * 128;
  {
    const int seg = t & 15;
    const int rb = t >> 4;
#pragma unroll
    for (int p = 0; p < 8; ++p) {
      const int r = rb + p * 16;
      const int gr = row0 + r;
      uint4 v = make_uint4(0u, 0u, 0u, 0u);
      if (gr < nrows) v = *(const uint4*)(X + (size_t)gr * 128 + seg * 8);
      *(uint4*)(Xs + r * 136 + seg * 8) = v;
    }
  }
  __syncthreads();
  const int lane = t & 63;
  const int wave = t >> 6;
  const int n0 = wave * 32;
  const int nl = lane & 15;
  const int quad = lane >> 4;

  bf16x8 bw[2][4];
#pragma unroll
  for (int nt = 0; nt < 2; ++nt)
#pragma unroll
    for (int kk = 0; kk < 4; ++kk)
      bw[nt][kk] = *(const bf16x8*)(W1t + (size_t)(n0 + nt * 16 + nl) * 128 + kk * 32 + quad * 8);

  f32x4 acc[8][2];
#pragma unroll
  for (int mt = 0; mt < 8; ++mt) {
    acc[mt][0] = (f32x4)0.0f;
    acc[mt][1] = (f32x4)0.0f;
  }
#pragma unroll
  for (int kk = 0; kk < 4; ++kk) {
#pragma unroll
    for (int mt = 0; mt < 8; ++mt) {
      bf16x8 a = *(const bf16x8*)(Xs + (mt * 16 + nl) * 136 + kk * 32 + quad * 8);
      acc[mt][0] = MFMA_BF16(a, bw[0][kk], acc[mt][0]);
      acc[mt][1] = MFMA_BF16(a, bw[1][kk], acc[mt][1]);
    }
  }
  __syncthreads();  // all GEMM1 A-reads complete before overwriting Xs with T
  // epilogue 1: bias + relu -> Xs (in place, bf16)
#pragma unroll
  for (int nt = 0; nt < 2; ++nt) {
    const int n = n0 + nt * 16 + nl;
    const float bias = b1[n];
#pragma unroll
    for (int mt = 0; mt < 8; ++mt)
#pragma unroll
      for (int r = 0; r < 4; ++r) {
        float v = acc[mt][nt][r] + bias;
        v = v > 0.f ? v : 0.f;
        Xs[(mt * 16 + quad * 4 + r) * 136 + n] = f2bf(v);
      }
  }
  __syncthreads();
  // GEMM2
#pragma unroll
  for (int nt = 0; nt < 2; ++nt)
#pragma unroll
    for (int kk = 0; kk < 4; ++kk)
      bw[nt][kk] = *(const bf16x8*)(W2t + (size_t)(n0 + nt * 16 + nl) * 128 + kk * 32 + quad * 8);
#pragma unroll
  for (int mt = 0; mt < 8; ++mt) {
    acc[mt][0] = (f32x4)0.0f;
    acc[mt][1] = (f32x4)0.0f;
  }
#pragma unroll
  for (int kk = 0; kk < 4; ++kk) {
#pragma unroll
    for (int mt = 0; mt < 8; ++mt) {
      bf16x8 a = *(const bf16x8*)(Xs + (mt * 16 + nl) * 136 + kk * 32 + quad * 8);
      acc[mt][0] = MFMA_BF16(a, bw[0][kk], acc[mt][0]);
      acc[mt][1] = MFMA_BF16(a, bw[1][kk], acc[mt][1]);
    }
  }
  __syncthreads();  // all GEMM2 A-reads complete before overwriting Xs with C
  // epilogue 2: bias; BN partials from registers; C -> Xs (bf16)
  float ssum[2] = {0.f, 0.f}, ssq[2] = {0.f, 0.f};
#pragma unroll
  for (int nt = 0; nt < 2; ++nt) {
    const int n = n0 + nt * 16 + nl;
    const float bias = b2[n];
#pragma unroll
    for (int mt = 0; mt < 8; ++mt)
#pragma unroll
      for (int r = 0; r < 4; ++r) {
        const int row = row0 + mt * 16 + quad * 4 + r;
        float v = acc[mt][nt][r] + bias;
        if (row < nrows) {
          ssum[nt] += v;
          ssq[nt] += v * v;
        }
        Xs[(mt * 16 + quad * 4 + r) * 136 + n] = f2bf(v);
      }
  }
#pragma unroll
  for (int nt = 0; nt < 2; ++nt) {
    float s = ssum[nt], q = ssq[nt];
    s += __shfl_xor(s, 16);
    q += __shfl_xor(q, 16);
    s += __shfl_xor(s, 32);
    q += __shfl_xor(q, 32);
    if (quad == 0) {
      const int n = n0 + nt * 16 + nl;
      part[(size_t)blockIdx.x * 256 + n] = s;
      part[(size_t)blockIdx.x * 256 + 128 + n] = q;
    }
  }
  __syncthreads();
  // coalesced Y store (same pattern as staging load)
  {
    const int seg = t & 15;
    const int rb = t >> 4;
#pragma unroll
    for (int p = 0; p < 8; ++p) {
      const int r = rb + p * 16;
      const int gr = row0 + r;
      if (gr < nrows)
        *(uint4*)(Y + (size_t)gr * 128 + seg * 8) = *(const uint4*)(Xs + r * 136 + seg * 8);
    }
  }
}

// ---- parallel column-reduce of PART + scale/shift compute (r12-proven, ~free)
__global__ __launch_bounds__(256) void bn_reduce_finalize(
    const float* __restrict__ part, int nblk, const float* __restrict__ g,
    const float* __restrict__ be, float invN, float* __restrict__ scsh) {
  __shared__ float red[2][128];
  const int c = blockIdx.x;  // 0..127
  const int t = threadIdx.x;
  const int half = t >> 7;
  const int tt = t & 127;
  const int col = c + half * 128;
  float s = 0.f;
  for (int b = tt; b < nblk; b += 128) s += part[(size_t)b * 256 + col];
  red[half][tt] = s;
  __syncthreads();
  for (int d = 64; d > 0; d >>= 1) {
    if (tt < d) red[half][tt] += red[half][tt + d];
    __syncthreads();
  }
  if (t == 0) {
    float mu = red[0][0] * invN;
    float var = red[1][0] * invN - mu * mu;
    float rstd = rsqrtf(var + 1e-5f);
    float sc = rstd * g[c];
    scsh[c] = sc;
    scsh[128 + c] = be[c] - mu * sc;
  }
}

// ---- pooling (fused layer-3 BN+relu via precomputed scsh) + final head, one block/graph
__global__ __launch_bounds__(256) void pool_final(
    const u16* __restrict__ Hh, const int* __restrict__ batch, const float* __restrict__ scsh,
    const float* __restrict__ f1w, const float* __restrict__ f1b, const float* __restrict__ f2w,
    const float* __restrict__ f2b, float* __restrict__ out, int nrows) {
  __shared__ float red[16][128];
  __shared__ float pr[128];
  __shared__ float tt[128];
  const int gid = blockIdx.x, t = threadIdx.x;
  int l = 0, r = nrows;
  while (l < r) {
    int m = (l + r) >> 1;
    if (batch[m] < gid) l = m + 1; else r = m;
  }
  const int s0 = l;
  r = nrows;
  while (l < r) {
    int m = (l + r) >> 1;
    if (batch[m] < gid + 1) l = m + 1; else r = m;
  }
  const int s1 = l;
  const int fl = t & 15;
  const int grp = t >> 4;
  float sc[8], sh[8];
#pragma unroll
  for (int i = 0; i < 8; ++i) {
    sc[i] = scsh[fl * 8 + i];
    sh[i] = scsh[128 + fl * 8 + i];
  }
  float a[8];
#pragma unroll
  for (int i = 0; i < 8; ++i) a[i] = 0.f;
  for (int i = s0 + grp; i < s1; i += 16) {
    uint4 v = *(const uint4*)(Hh + (size_t)i * 128 + fl * 8);
    const u16* pp = (const u16*)&v;
#pragma unroll
    for (int k = 0; k < 8; ++k) {
      float xv = bf2f(pp[k]) * sc[k] + sh[k];
      a[k] += xv > 0.f ? xv : 0.f;
    }
  }
#pragma unroll
  for (int k = 0; k < 8; ++k) red[grp][fl * 8 + k] = a[k];
  __syncthreads();
  if (t < 128) {
    float s = 0.f;
#pragma unroll
    for (int gg2 = 0; gg2 < 16; ++gg2) s += red[gg2][t];
    pr[t] = s;
  }
  __syncthreads();
  if (t < 128) {
    float s = f1b[t];
    for (int k = 0; k < 128; ++k) s += pr[k] * f1w[k * 128 + t];
    tt[t] = s > 0.f ? s : 0.f;
  }
  __syncthreads();
  if (t < 10) {
    float s2 = f2b[t];
    for (int k = 0; k < 128; ++k) s2 += tt[k] * f2w[k * 10 + t];
    out[gid * 10 + t] = s2;
  }
}

// ws layout (bytes):
//   H     @ 0          : 25,600,000  (bf16 node features)
//   AGG   @ 25,600,000 : 25,600,000  (bf16 aggregated, layer input tiles)
//   PAIRS @ 51,200,000 : 512*4608*4 = 9,437,184
//   CSR   @ 60,637,184 : 9,437,184
//   RS    @ 70,074,368 : 400,000
//   DEG   @ 70,474,368 : 400,000
//   CUR   @ 70,874,368 : 2,048       (zeroed)
//   SCSH  @ 70,876,416 : 3,072       (3 layers x 256 f32; written by bn_reduce_finalize)
//   WT    @ 70,879,488 : 196,608
//   TBL   @ 71,076,096 : 128,000
//   PART  @ 71,204,096 : 782*256*4 = 800,768 (per-block BN partials; fully overwritten)
extern "C" void kernel_launch(void* const* d_in, const int* in_sizes, int n_in, void* d_out,
                              int out_size, void* d_ws, size_t ws_size, hipStream_t stream) {
  const int* x = (const int*)d_in[0];
  const int* ei = (const int*)d_in[1];
  const int* batch = (const int*)d_in[2];
  const float* emb = (const float*)d_in[3];
  const float* iw1 = (const float*)d_in[4];
  const float* ib1 = (const float*)d_in[5];
  const float* iw2 = (const float*)d_in[6];
  const float* ib2 = (const float*)d_in[7];
  const float* f1w = (const float*)d_in[8];
  const float* f1b = (const float*)d_in[9];
  const float* f2w = (const float*)d_in[10];
  const float* f2b = (const float*)d_in[11];
  const float* cw1[3] = {(const float*)d_in[12], (const float*)d_in[18], (const float*)d_in[24]};
  const float* cb1[3] = {(const float*)d_in[13], (const float*)d_in[19], (const float*)d_in[25]};
  const float* cw2[3] = {(const float*)d_in[14], (const float*)d_in[20], (const float*)d_in[26]};
  const float* cb2[3] = {(const float*)d_in[15], (const float*)d_in[21], (const float*)d_in[27]};
  const float* gg[3] = {(const float*)d_in[16], (const float*)d_in[22], (const float*)d_in[28]};
  const float* bb[3] = {(const float*)d_in[17], (const float*)d_in[23], (const float*)d_in[29]};

  const int N_ = in_sizes[0];
  const int E_ = in_sizes[1] / 2;
  const int V_ = in_sizes[3] / 128;
  const int G_ = out_size / 10;
  const int NBUC = (N_ + 255) >> 8;
  const float invN = 1.0f / (float)N_;

  char* ws = (char*)d_ws;
  u16* H = (u16*)(ws + 0);
  u16* AGG = (u16*)(ws + 25600000);
  u32* PAIRS = (u32*)(ws + 51200000);
  u32* CSR = (u32*)(ws + 60637184);
  int* RS = (int*)(ws + 70074368);
  int* DEG = (int*)(ws + 70474368);
  u32* CUR = (u32*)(ws + 70874368);
  float* SCSH = (float*)(ws + 70876416);
  u16* WT = (u16*)(ws + 70879488);
  u16* TBL = (u16*)(ws + 71076096);
  float* PART = (float*)(ws + 71204096);

  hipMemsetAsync(ws + 70874368, 0, 2048, stream);  // CUR only

  prep_w6<<<384, 256, 0, stream>>>(cw1[0], cw2[0], cw1[1], cw2[1], cw1[2], cw2[2], WT);
  mlp0_table<<<V_, 128, 0, stream>>>(emb, iw1, ib1, iw2, ib2, TBL);
  bucket_scatter<<<(E_ + EPB - 1) / EPB, 256, 0, stream>>>(ei, ei + E_, PAIRS, CUR, E_, NBUC);
  csr_build<<<NBUC, 256, 0, stream>>>(PAIRS, CUR, CSR, RS, DEG, N_);

  const int ablk = (N_ + 3) / 4;
  const int mblk = (N_ + 127) / 128;
  for (int l = 0; l < 3; ++l) {
    const u16* W1 = WT + (size_t)l * 32768;
    const u16* W2 = WT + (size_t)l * 32768 + 16384;
    if (l == 0)
      agg_kernel<0><<<ablk, 256, 0, stream>>>(TBL, x, CSR, RS, DEG, nullptr, AGG, N_);
    else
      agg_kernel<1><<<ablk, 256, 0, stream>>>(H, nullptr, CSR, RS, DEG, SCSH + (l - 1) * 256,
                                              AGG, N_);
    mlp_kernel<<<mblk, 256, 0, stream>>>(AGG, W1, cb1[l], W2, cb2[l], H, PART, N_);
    bn_reduce_finalize<<<128, 256, 0, stream>>>(PART, mblk, gg[l], bb[l], invN,
                                                SCSH + l * 256);
  }
  pool_final<<<G_, 256, 0, stream>>>(H, batch, SCSH + 2 * 256, f1w, f1b, f2w, f2b,
                                     (float*)d_out, N_);
}

// Round 15
// 463.856 us; speedup vs baseline: 1.2299x; 1.0043x over previous
//
#include <hip/hip_runtime.h>

typedef unsigned short u16;
typedef unsigned int u32;
typedef __bf16 bf16x8 __attribute__((ext_vector_type(8)));
typedef float f32x4 __attribute__((ext_vector_type(4)));

#define MFMA_BF16(a, b, c) __builtin_amdgcn_mfma_f32_16x16x32_bf16(a, b, c, 0, 0, 0)

#define NBUC_MAX 512
#define BCAP 4608
#define EPB 2048  // edges per block in bucket_scatter (782 blocks = 3/CU)

__device__ __forceinline__ float bf2f(u16 h) {
  u32 u = ((u32)h) << 16;
  return __builtin_bit_cast(float, u);
}
__device__ __forceinline__ u16 f2bf_sw(float f) {
  u32 u = __builtin_bit_cast(u32, f);
  u += 0x7fffu + ((u >> 16) & 1u);
  return (u16)(u >> 16);
}
// packed f32x2 -> bf16x2 (u32). HW v_cvt_pk_bf16_f32 on gfx950 (1 inst vs ~9 sw).
// r14: WIN in mlp epilogues (~13 us). Loop-body pk-math asm: LOSS (r10, r14) — do
// not reintroduce v_pk_fma/add asm into agg's inner loop.
#if __has_builtin(__builtin_amdgcn_cvt_pk_bf16_f32)
__device__ __forceinline__ u32 f2bf_pk(float a, float b) {
  auto r = __builtin_amdgcn_cvt_pk_bf16_f32(a, b);
  return __builtin_bit_cast(u32, r);
}
#else
__device__ __forceinline__ u32 f2bf_pk(float a, float b) {
  return (u32)f2bf_sw(a) | ((u32)f2bf_sw(b) << 16);
}
#endif
__device__ __forceinline__ u16 f2bf(float f) { return (u16)f2bf_pk(f, f); }

// ---- weight prep: 6 conv weights fp32 [k][n] -> bf16 transposed [n][k], one dispatch
__global__ __launch_bounds__(256) void prep_w6(const float* __restrict__ w0,
                                               const float* __restrict__ w1,
                                               const float* __restrict__ w2,
                                               const float* __restrict__ w3,
                                               const float* __restrict__ w4,
                                               const float* __restrict__ w5,
                                               u16* __restrict__ wt) {
  const int which = blockIdx.x >> 6;
  const float* w = which == 0 ? w0 : which == 1 ? w1 : which == 2 ? w2
                  : which == 3 ? w3 : which == 4 ? w4 : w5;
  int t = (blockIdx.x & 63) * 256 + threadIdx.x;  // 16384 elems per matrix
  int n = t >> 7, k = t & 127;
  wt[which * 16384 + n * 128 + k] = f2bf(w[k * 128 + n]);
}

// ---- initial MLP applied to the 500-row embedding table (h0 = table2[x])
__global__ __launch_bounds__(128) void mlp0_table(
    const float* __restrict__ emb, const float* __restrict__ w1, const float* __restrict__ b1,
    const float* __restrict__ w2, const float* __restrict__ b2, u16* __restrict__ table) {
  __shared__ float e[128];
  __shared__ float tt[128];
  int r = blockIdx.x, j = threadIdx.x;
  e[j] = emb[r * 128 + j];
  __syncthreads();
  float s = b1[j];
  for (int k = 0; k < 128; ++k) s += e[k] * w1[k * 128 + j];
  tt[j] = s > 0.f ? s : 0.f;
  __syncthreads();
  float s2 = b2[j];
  for (int k = 0; k < 128; ++k) s2 += tt[k] * w2[k * 128 + j];
  table[r * 128 + j] = f2bf(s2);
}

// ---- pass 1: bucket edges by dst>>8, packed (src<<8)|dloc. No LDS staging; LDS = 4 KB.
__global__ __launch_bounds__(256) void bucket_scatter(const int* __restrict__ src,
                                                      const int* __restrict__ dst,
                                                      u32* __restrict__ pairs,
                                                      u32* __restrict__ cursor, int E_, int nbuc) {
  __shared__ u32 lcnt[NBUC_MAX];
  __shared__ u32 lbase[NBUC_MAX];
  const int t = threadIdx.x;
  for (int b = t; b < NBUC_MAX; b += 256) lcnt[b] = 0;
  __syncthreads();
  const int e0 = blockIdx.x * EPB;
#pragma unroll
  for (int it = 0; it < EPB / 256; ++it) {
    int e = e0 + it * 256 + t;
    if (e < E_) atomicAdd(&lcnt[((u32)dst[e]) >> 8], 1u);
  }
  __syncthreads();
  for (int b = t; b < nbuc; b += 256) {
    u32 c = lcnt[b];
    lbase[b] = c ? atomicAdd(&cursor[b], c) : 0u;
    lcnt[b] = 0;
  }
  __syncthreads();
#pragma unroll
  for (int it = 0; it < EPB / 256; ++it) {
    int e = e0 + it * 256 + t;
    if (e < E_) {
      int d = dst[e];
      u32 b = ((u32)d) >> 8;
      u32 r = atomicAdd(&lcnt[b], 1u);
      u32 p = lbase[b] + r;
      if (p < BCAP) pairs[(size_t)b * BCAP + p] = (((u32)src[e]) << 8) | (u32)(d & 255);
    }
  }
}

// ---- pass 2: per-bucket exact CSR (256 nodes/bucket): LDS count + scan + rank scatter
__global__ __launch_bounds__(256) void csr_build(const u32* __restrict__ pairs,
                                                 const u32* __restrict__ cursor,
                                                 u32* __restrict__ csr, int* __restrict__ RS,
                                                 int* __restrict__ DEG, int nrows) {
  __shared__ u32 cnt[256];
  __shared__ u32 offs[256];
  __shared__ u32 basearr[256];
  const int b = blockIdx.x, t = threadIdx.x;
  u32 count = cursor[b];
  if (count > BCAP) count = BCAP;
  cnt[t] = 0;
  __syncthreads();
  const u32* pb = pairs + (size_t)b * BCAP;
  for (u32 i = t; i < count; i += 256) atomicAdd(&cnt[pb[i] & 255u], 1u);
  __syncthreads();
  const u32 my = cnt[t];
  offs[t] = my;
  __syncthreads();
  for (int d = 1; d < 256; d <<= 1) {
    u32 v = (t >= d) ? offs[t - d] : 0u;
    __syncthreads();
    offs[t] += v;
    __syncthreads();
  }
  const u32 excl = offs[t] - my;  // exclusive prefix
  const int node = (b << 8) + t;
  if (node < nrows) {
    RS[node] = b * BCAP + (int)excl;
    DEG[node] = (int)my;
  }
  basearr[t] = excl;
  cnt[t] = 0;
  __syncthreads();
  for (u32 i = t; i < count; i += 256) {
    u32 v = pb[i];
    u32 dl = v & 255u;
    u32 r = atomicAdd(&cnt[dl], 1u);
    csr[(size_t)b * BCAP + basearr[dl] + r] = v >> 8;
  }
}

// ---- aggregation (EXACT r13 inner loop — 69.0 us, VALU 65%, its measured floor):
// AGG[i] = f(row(i)) + sum_j f(row(j)).  MODE 0: row(i)=TBL[x[i]], f=id.
// MODE 1: row(i)=H[i], f=BN-affine+relu (scsh precomputed). Fused per-edge BN (r9:
// separate pass nets worse). SCALAR f32 math in ACCUM — v_pk asm regressed twice
// (r10: +VGPR/no lowering; r14: 69.0->72.9, VALU 66->73%). 2-deep pipeline (r6).
// 32-bit byte offsets. Output conversion via cvt_pk (epilogue-only, safe).
template <int MODE>
__global__ __launch_bounds__(256) void agg_kernel(
    const u16* __restrict__ Hsrc, const int* __restrict__ x, const u32* __restrict__ csr,
    const int* __restrict__ RS, const int* __restrict__ DEG, const float* __restrict__ scsh,
    u16* __restrict__ AGG, int nrows) {
  int node = blockIdx.x * 4 + (threadIdx.x >> 6);
  if (node >= nrows) return;
  const int lane = threadIdx.x & 63;
  const int grp = lane >> 4;  // neighbor sub-slot 0..3
  const int fl = lane & 15;   // 16B feature chunk
  const int deg = DEG[node];
  const u32* cl = csr + RS[node];
  const char* Hb = (const char*)Hsrc;
  const u32 flo = (u32)fl << 4;

  float sc[8], sh[8];
  if (MODE == 1) {
#pragma unroll
    for (int i = 0; i < 8; ++i) {
      sc[i] = scsh[fl * 8 + i];
      sh[i] = scsh[128 + fl * 8 + i];
    }
  }
  float a[8];
#pragma unroll
  for (int i = 0; i < 8; ++i) a[i] = 0.f;

#define ACCUM(vv)                                   \
  {                                                 \
    const u16* p = (const u16*)&(vv);               \
    _Pragma("unroll") for (int i = 0; i < 8; ++i) { \
      float xv = bf2f(p[i]);                        \
      if (MODE == 1) {                              \
        xv = xv * sc[i] + sh[i];                    \
        xv = xv > 0.f ? xv : 0.f;                   \
      }                                             \
      a[i] += xv;                                   \
    }                                               \
  }
#define ROWOFF(idx) ((((u32)(MODE == 0 ? x[(idx)] : (idx))) << 8) + flo)

  if (grp == 0) {
    uint4 v = *(const uint4*)(Hb + ROWOFF(node));
    ACCUM(v);
  }
  int j = grp;
  int cA = (j < deg) ? (int)cl[j] : 0;
  int cB = (j + 4 < deg) ? (int)cl[j + 4] : 0;
  uint4 nv = make_uint4(0u, 0u, 0u, 0u);
  if (j < deg) nv = *(const uint4*)(Hb + ROWOFF(cA));
  while (j < deg) {
    uint4 cv = nv;
    int cn = cB;
    cB = (j + 8 < deg) ? (int)cl[j + 8] : 0;
    if (j + 4 < deg) nv = *(const uint4*)(Hb + ROWOFF(cn));
    ACCUM(cv);
    j += 4;
  }
#undef ROWOFF
#undef ACCUM

#pragma unroll
  for (int i = 0; i < 8; ++i) {
    a[i] += __shfl_xor(a[i], 16);
    a[i] += __shfl_xor(a[i], 32);
  }
  if (grp == 0) {
    u32 o[4];
#pragma unroll
    for (int i = 0; i < 4; ++i) o[i] = f2bf_pk(a[2 * i], a[2 * i + 1]);
    *(uint4*)(AGG + (size_t)node * 128 + fl * 8) = *(uint4*)o;
  }
}

// ---- fused 2-layer MLP (bf16 MFMA), 128-row x 128-col tile, 4 waves, T in-place,
// C routed through Xs then coalesced uint4 store (r13). Epilogue conversions via
// v_cvt_pk_bf16_f32 (r14 win, ~13 us total). BN stats -> PART (r12).
__global__ __launch_bounds__(256) void mlp_kernel(
    const u16* __restrict__ X, const u16* __restrict__ W1t, const float* __restrict__ b1,
    const u16* __restrict__ W2t, const float* __restrict__ b2, u16* __restrict__ Y,
    float* __restrict__ part, int nrows) {
  __shared__ u16 Xs[128 * 136];
  const int t = threadIdx.x;
  const int row0 = blockIdx.x * 128;
  {
    const int seg = t & 15;
    const int rb = t >> 4;
#pragma unroll
    for (int p = 0; p < 8; ++p) {
      const int r = rb + p * 16;
      const int gr = row0 + r;
      uint4 v = make_uint4(0u, 0u, 0u, 0u);
      if (gr < nrows) v = *(const uint4*)(X + (size_t)gr * 128 + seg * 8);
      *(uint4*)(Xs + r * 136 + seg * 8) = v;
    }
  }
  __syncthreads();
  const int lane = t & 63;
  const int wave = t >> 6;
  const int n0 = wave * 32;
  const int nl = lane & 15;
  const int quad = lane >> 4;

  bf16x8 bw[2][4];
#pragma unroll
  for (int nt = 0; nt < 2; ++nt)
#pragma unroll
    for (int kk = 0; kk < 4; ++kk)
      bw[nt][kk] = *(const bf16x8*)(W1t + (size_t)(n0 + nt * 16 + nl) * 128 + kk * 32 + quad * 8);

  f32x4 acc[8][2];
#pragma unroll
  for (int mt = 0; mt < 8; ++mt) {
    acc[mt][0] = (f32x4)0.0f;
    acc[mt][1] = (f32x4)0.0f;
  }
#pragma unroll
  for (int kk = 0; kk < 4; ++kk) {
#pragma unroll
    for (int mt = 0; mt < 8; ++mt) {
      bf16x8 a = *(const bf16x8*)(Xs + (mt * 16 + nl) * 136 + kk * 32 + quad * 8);
      acc[mt][0] = MFMA_BF16(a, bw[0][kk], acc[mt][0]);
      acc[mt][1] = MFMA_BF16(a, bw[1][kk], acc[mt][1]);
    }
  }
  __syncthreads();  // all GEMM1 A-reads complete before overwriting Xs with T
  // epilogue 1: bias + relu -> Xs (in place, bf16)
#pragma unroll
  for (int nt = 0; nt < 2; ++nt) {
    const int n = n0 + nt * 16 + nl;
    const float bias = b1[n];
#pragma unroll
    for (int mt = 0; mt < 8; ++mt)
#pragma unroll
      for (int r = 0; r < 4; ++r) {
        float v = acc[mt][nt][r] + bias;
        v = v > 0.f ? v : 0.f;
        Xs[(mt * 16 + quad * 4 + r) * 136 + n] = f2bf(v);
      }
  }
  __syncthreads();
  // GEMM2
#pragma unroll
  for (int nt = 0; nt < 2; ++nt)
#pragma unroll
    for (int kk = 0; kk < 4; ++kk)
      bw[nt][kk] = *(const bf16x8*)(W2t + (size_t)(n0 + nt * 16 + nl) * 128 + kk * 32 + quad * 8);
#pragma unroll
  for (int mt = 0; mt < 8; ++mt) {
    acc[mt][0] = (f32x4)0.0f;
    acc[mt][1] = (f32x4)0.0f;
  }
#pragma unroll
  for (int kk = 0; kk < 4; ++kk) {
#pragma unroll
    for (int mt = 0; mt < 8; ++mt) {
      bf16x8 a = *(const bf16x8*)(Xs + (mt * 16 + nl) * 136 + kk * 32 + quad * 8);
      acc[mt][0] = MFMA_BF16(a, bw[0][kk], acc[mt][0]);
      acc[mt][1] = MFMA_BF16(a, bw[1][kk], acc[mt][1]);
    }
  }
  __syncthreads();  // all GEMM2 A-reads complete before overwriting Xs with C
  // epilogue 2: bias; BN partials from registers; C -> Xs (bf16)
  float ssum[2] = {0.f, 0.f}, ssq[2] = {0.f, 0.f};
#pragma unroll
  for (int nt = 0; nt < 2; ++nt) {
    const int n = n0 + nt * 16 + nl;
    const float bias = b2[n];
#pragma unroll
    for (int mt = 0; mt < 8; ++mt)
#pragma unroll
      for (int r = 0; r < 4; ++r) {
        const int row = row0 + mt * 16 + quad * 4 + r;
        float v = acc[mt][nt][r] + bias;
        if (row < nrows) {
          ssum[nt] += v;
          ssq[nt] += v * v;
        }
        Xs[(mt * 16 + quad * 4 + r) * 136 + n] = f2bf(v);
      }
  }
#pragma unroll
  for (int nt = 0; nt < 2; ++nt) {
    float s = ssum[nt], q = ssq[nt];
    s += __shfl_xor(s, 16);
    q += __shfl_xor(q, 16);
    s += __shfl_xor(s, 32);
    q += __shfl_xor(q, 32);
    if (quad == 0) {
      const int n = n0 + nt * 16 + nl;
      part[(size_t)blockIdx.x * 256 + n] = s;
      part[(size_t)blockIdx.x * 256 + 128 + n] = q;
    }
  }
  __syncthreads();
  // coalesced Y store (same pattern as staging load)
  {
    const int seg = t & 15;
    const int rb = t >> 4;
#pragma unroll
    for (int p = 0; p < 8; ++p) {
      const int r = rb + p * 16;
      const int gr = row0 + r;
      if (gr < nrows)
        *(uint4*)(Y + (size_t)gr * 128 + seg * 8) = *(const uint4*)(Xs + r * 136 + seg * 8);
    }
  }
}

// ---- parallel column-reduce of PART + scale/shift compute (r12-proven, ~free)
__global__ __launch_bounds__(256) void bn_reduce_finalize(
    const float* __restrict__ part, int nblk, const float* __restrict__ g,
    const float* __restrict__ be, float invN, float* __restrict__ scsh) {
  __shared__ float red[2][128];
  const int c = blockIdx.x;  // 0..127
  const int t = threadIdx.x;
  const int half = t >> 7;
  const int tt = t & 127;
  const int col = c + half * 128;
  float s = 0.f;
  for (int b = tt; b < nblk; b += 128) s += part[(size_t)b * 256 + col];
  red[half][tt] = s;
  __syncthreads();
  for (int d = 64; d > 0; d >>= 1) {
    if (tt < d) red[half][tt] += red[half][tt + d];
    __syncthreads();
  }
  if (t == 0) {
    float mu = red[0][0] * invN;
    float var = red[1][0] * invN - mu * mu;
    float rstd = rsqrtf(var + 1e-5f);
    float sc = rstd * g[c];
    scsh[c] = sc;
    scsh[128 + c] = be[c] - mu * sc;
  }
}

// ---- pooling (fused layer-3 BN+relu via precomputed scsh) + final head, one block/graph
__global__ __launch_bounds__(256) void pool_final(
    const u16* __restrict__ Hh, const int* __restrict__ batch, const float* __restrict__ scsh,
    const float* __restrict__ f1w, const float* __restrict__ f1b, const float* __restrict__ f2w,
    const float* __restrict__ f2b, float* __restrict__ out, int nrows) {
  __shared__ float red[16][128];
  __shared__ float pr[128];
  __shared__ float tt[128];
  const int gid = blockIdx.x, t = threadIdx.x;
  int l = 0, r = nrows;
  while (l < r) {
    int m = (l + r) >> 1;
    if (batch[m] < gid) l = m + 1; else r = m;
  }
  const int s0 = l;
  r = nrows;
  while (l < r) {
    int m = (l + r) >> 1;
    if (batch[m] < gid + 1) l = m + 1; else r = m;
  }
  const int s1 = l;
  const int fl = t & 15;
  const int grp = t >> 4;
  float sc[8], sh[8];
#pragma unroll
  for (int i = 0; i < 8; ++i) {
    sc[i] = scsh[fl * 8 + i];
    sh[i] = scsh[128 + fl * 8 + i];
  }
  float a[8];
#pragma unroll
  for (int i = 0; i < 8; ++i) a[i] = 0.f;
  for (int i = s0 + grp; i < s1; i += 16) {
    uint4 v = *(const uint4*)(Hh + (size_t)i * 128 + fl * 8);
    const u16* pp = (const u16*)&v;
#pragma unroll
    for (int k = 0; k < 8; ++k) {
      float xv = bf2f(pp[k]) * sc[k] + sh[k];
      a[k] += xv > 0.f ? xv : 0.f;
    }
  }
#pragma unroll
  for (int k = 0; k < 8; ++k) red[grp][fl * 8 + k] = a[k];
  __syncthreads();
  if (t < 128) {
    float s = 0.f;
#pragma unroll
    for (int gg2 = 0; gg2 < 16; ++gg2) s += red[gg2][t];
    pr[t] = s;
  }
  __syncthreads();
  if (t < 128) {
    float s = f1b[t];
    for (int k = 0; k < 128; ++k) s += pr[k] * f1w[k * 128 + t];
    tt[t] = s > 0.f ? s : 0.f;
  }
  __syncthreads();
  if (t < 10) {
    float s2 = f2b[t];
    for (int k = 0; k < 128; ++k) s2 += tt[k] * f2w[k * 10 + t];
    out[gid * 10 + t] = s2;
  }
}

// ws layout (bytes):
//   H     @ 0          : 25,600,000  (bf16 node features)
//   AGG   @ 25,600,000 : 25,600,000  (bf16 aggregated, layer input tiles)
//   PAIRS @ 51,200,000 : 512*4608*4 = 9,437,184
//   CSR   @ 60,637,184 : 9,437,184
//   RS    @ 70,074,368 : 400,000
//   DEG   @ 70,474,368 : 400,000
//   CUR   @ 70,874,368 : 2,048       (zeroed)
//   SCSH  @ 70,876,416 : 3,072       (3 layers x 256 f32; written by bn_reduce_finalize)
//   WT    @ 70,879,488 : 196,608
//   TBL   @ 71,076,096 : 128,000
//   PART  @ 71,204,096 : 782*256*4 = 800,768 (per-block BN partials; fully overwritten)
extern "C" void kernel_launch(void* const* d_in, const int* in_sizes, int n_in, void* d_out,
                              int out_size, void* d_ws, size_t ws_size, hipStream_t stream) {
  const int* x = (const int*)d_in[0];
  const int* ei = (const int*)d_in[1];
  const int* batch = (const int*)d_in[2];
  const float* emb = (const float*)d_in[3];
  const float* iw1 = (const float*)d_in[4];
  const float* ib1 = (const float*)d_in[5];
  const float* iw2 = (const float*)d_in[6];
  const float* ib2 = (const float*)d_in[7];
  const float* f1w = (const float*)d_in[8];
  const float* f1b = (const float*)d_in[9];
  const float* f2w = (const float*)d_in[10];
  const float* f2b = (const float*)d_in[11];
  const float* cw1[3] = {(const float*)d_in[12], (const float*)d_in[18], (const float*)d_in[24]};
  const float* cb1[3] = {(const float*)d_in[13], (const float*)d_in[19], (const float*)d_in[25]};
  const float* cw2[3] = {(const float*)d_in[14], (const float*)d_in[20], (const float*)d_in[26]};
  const float* cb2[3] = {(const float*)d_in[15], (const float*)d_in[21], (const float*)d_in[27]};
  const float* gg[3] = {(const float*)d_in[16], (const float*)d_in[22], (const float*)d_in[28]};
  const float* bb[3] = {(const float*)d_in[17], (const float*)d_in[23], (const float*)d_in[29]};

  const int N_ = in_sizes[0];
  const int E_ = in_sizes[1] / 2;
  const int V_ = in_sizes[3] / 128;
  const int G_ = out_size / 10;
  const int NBUC = (N_ + 255) >> 8;
  const float invN = 1.0f / (float)N_;

  char* ws = (char*)d_ws;
  u16* H = (u16*)(ws + 0);
  u16* AGG = (u16*)(ws + 25600000);
  u32* PAIRS = (u32*)(ws + 51200000);
  u32* CSR = (u32*)(ws + 60637184);
  int* RS = (int*)(ws + 70074368);
  int* DEG = (int*)(ws + 70474368);
  u32* CUR = (u32*)(ws + 70874368);
  float* SCSH = (float*)(ws + 70876416);
  u16* WT = (u16*)(ws + 70879488);
  u16* TBL = (u16*)(ws + 71076096);
  float* PART = (float*)(ws + 71204096);

  hipMemsetAsync(ws + 70874368, 0, 2048, stream);  // CUR only

  prep_w6<<<384, 256, 0, stream>>>(cw1[0], cw2[0], cw1[1], cw2[1], cw1[2], cw2[2], WT);
  mlp0_table<<<V_, 128, 0, stream>>>(emb, iw1, ib1, iw2, ib2, TBL);
  bucket_scatter<<<(E_ + EPB - 1) / EPB, 256, 0, stream>>>(ei, ei + E_, PAIRS, CUR, E_, NBUC);
  csr_build<<<NBUC, 256, 0, stream>>>(PAIRS, CUR, CSR, RS, DEG, N_);

  const int ablk = (N_ + 3) / 4;
  const int mblk = (N_ + 127) / 128;
  for (int l = 0; l < 3; ++l) {
    const u16* W1 = WT + (size_t)l * 32768;
    const u16* W2 = WT + (size_t)l * 32768 + 16384;
    if (l == 0)
      agg_kernel<0><<<ablk, 256, 0, stream>>>(TBL, x, CSR, RS, DEG, nullptr, AGG, N_);
    else
      agg_kernel<1><<<ablk, 256, 0, stream>>>(H, nullptr, CSR, RS, DEG, SCSH + (l - 1) * 256,
                                              AGG, N_);
    mlp_kernel<<<mblk, 256, 0, stream>>>(AGG, W1, cb1[l], W2, cb2[l], H, PART, N_);
    bn_reduce_finalize<<<128, 256, 0, stream>>>(PART, mblk, gg[l], bb[l], invN,
                                                SCSH + l * 256);
  }
  pool_final<<<G_, 256, 0, stream>>>(H, batch, SCSH + 2 * 256, f1w, f1b, f2w, f2b,
                                     (float*)d_out, N_);
}

// Round 16
// 454.434 us; speedup vs baseline: 1.2554x; 1.0207x over previous
//
#include <hip/hip_runtime.h>

typedef unsigned short u16;
typedef unsigned int u32;
typedef __bf16 bf16x8 __attribute__((ext_vector_type(8)));
typedef float f32x4 __attribute__((ext_vector_type(4)));

#define MFMA_BF16(a, b, c) __builtin_amdgcn_mfma_f32_16x16x32_bf16(a, b, c, 0, 0, 0)

#define NBUC_MAX 512
#define BCAP 4608
#define EPB 2048  // edges per bucket-scatter block

__device__ __forceinline__ float bf2f(u16 h) {
  u32 u = ((u32)h) << 16;
  return __builtin_bit_cast(float, u);
}
__device__ __forceinline__ u16 f2bf_sw(float f) {
  u32 u = __builtin_bit_cast(u32, f);
  u += 0x7fffu + ((u >> 16) & 1u);
  return (u16)(u >> 16);
}
// packed f32x2 -> bf16x2. HW cvt: WIN in epilogues (r14). Loop-body pk-math asm:
// LOSS twice (r10, r14) — never again in agg's inner loop.
#if __has_builtin(__builtin_amdgcn_cvt_pk_bf16_f32)
__device__ __forceinline__ u32 f2bf_pk(float a, float b) {
  auto r = __builtin_amdgcn_cvt_pk_bf16_f32(a, b);
  return __builtin_bit_cast(u32, r);
}
#else
__device__ __forceinline__ u32 f2bf_pk(float a, float b) {
  return (u32)f2bf_sw(a) | ((u32)f2bf_sw(b) << 16);
}
#endif
__device__ __forceinline__ u16 f2bf(float f) { return (u16)f2bf_pk(f, f); }

// ---- fused setup: [0,384) weight prep | [384,384+V) mlp0 table | rest: bucket scatter.
// One dispatch instead of three: kills 2 serial gaps; prep/mlp0 hide inside bucket.
// Bucket edge reads vectorized to int4 (was 24 scalar 4B loads/thread).
__global__ __launch_bounds__(256) void setup_all(
    const float* __restrict__ w0, const float* __restrict__ w1c, const float* __restrict__ w2c,
    const float* __restrict__ w3, const float* __restrict__ w4, const float* __restrict__ w5,
    u16* __restrict__ wt, const float* __restrict__ emb, const float* __restrict__ iw1,
    const float* __restrict__ ib1, const float* __restrict__ iw2, const float* __restrict__ ib2,
    u16* __restrict__ table, int V_, const int* __restrict__ src, const int* __restrict__ dst,
    u32* __restrict__ pairs, u32* __restrict__ cursor, int E_, int nbuc) {
  __shared__ u32 smem[1024];  // bucket: lcnt|lbase ; mlp0: e|tt (aliased)
  const int t = threadIdx.x;
  int bid = blockIdx.x;
  if (bid < 384) {  // ---- weight prep
    const int which = bid >> 6;
    const float* w = which == 0 ? w0 : which == 1 ? w1c : which == 2 ? w2c
                    : which == 3 ? w3 : which == 4 ? w4 : w5;
    int tt_ = (bid & 63) * 256 + t;
    int n = tt_ >> 7, k = tt_ & 127;
    wt[which * 16384 + n * 128 + k] = f2bf(w[k * 128 + n]);
    return;
  }
  bid -= 384;
  if (bid < V_) {  // ---- initial MLP on the 500-row embedding table
    float* e = (float*)smem;
    float* tb = e + 128;
    if (t < 128) e[t] = emb[bid * 128 + t];
    __syncthreads();
    if (t < 128) {
      float s = ib1[t];
      for (int k = 0; k < 128; ++k) s += e[k] * iw1[k * 128 + t];
      tb[t] = s > 0.f ? s : 0.f;
    }
    __syncthreads();
    if (t < 128) {
      float s2 = ib2[t];
      for (int k = 0; k < 128; ++k) s2 += tb[k] * iw2[k * 128 + t];
      table[bid * 128 + t] = f2bf(s2);
    }
    return;
  }
  bid -= V_;
  {  // ---- bucket edges by dst>>8, packed (src<<8)|dloc
    u32* lcnt = smem;
    u32* lbase = smem + 512;
    for (int b = t; b < NBUC_MAX; b += 256) lcnt[b] = 0;
    __syncthreads();
    const int e0 = bid * EPB;
#pragma unroll
    for (int it = 0; it < EPB / 1024; ++it) {
      int e = e0 + it * 1024 + t * 4;
      if (e + 3 < E_) {
        int4 d4 = *(const int4*)(dst + e);
        atomicAdd(&lcnt[((u32)d4.x) >> 8], 1u);
        atomicAdd(&lcnt[((u32)d4.y) >> 8], 1u);
        atomicAdd(&lcnt[((u32)d4.z) >> 8], 1u);
        atomicAdd(&lcnt[((u32)d4.w) >> 8], 1u);
      } else {
        for (int k = 0; k < 4; ++k)
          if (e + k < E_) atomicAdd(&lcnt[((u32)dst[e + k]) >> 8], 1u);
      }
    }
    __syncthreads();
    for (int b = t; b < nbuc; b += 256) {
      u32 c = lcnt[b];
      lbase[b] = c ? atomicAdd(&cursor[b], c) : 0u;
      lcnt[b] = 0;
    }
    __syncthreads();
#define PUTPAIR(dd, ss)                                            \
  {                                                                \
    u32 b_ = ((u32)(dd)) >> 8;                                     \
    u32 r_ = atomicAdd(&lcnt[b_], 1u);                             \
    u32 p_ = lbase[b_] + r_;                                       \
    if (p_ < BCAP)                                                 \
      pairs[(size_t)b_ * BCAP + p_] = (((u32)(ss)) << 8) | (u32)((dd) & 255); \
  }
#pragma unroll
    for (int it = 0; it < EPB / 1024; ++it) {
      int e = e0 + it * 1024 + t * 4;
      if (e + 3 < E_) {
        int4 d4 = *(const int4*)(dst + e);
        int4 s4 = *(const int4*)(src + e);
        PUTPAIR(d4.x, s4.x)
        PUTPAIR(d4.y, s4.y)
        PUTPAIR(d4.z, s4.z)
        PUTPAIR(d4.w, s4.w)
      } else {
        for (int k = 0; k < 4; ++k)
          if (e + k < E_) PUTPAIR(dst[e + k], src[e + k])
      }
    }
#undef PUTPAIR
  }
}

// ---- per-bucket exact CSR (256 nodes/bucket): LDS count + scan + rank scatter.
// Pair reads vectorized to uint4 (was 32 scalar loads/thread).
__global__ __launch_bounds__(256) void csr_build(const u32* __restrict__ pairs,
                                                 const u32* __restrict__ cursor,
                                                 u32* __restrict__ csr, int* __restrict__ RS,
                                                 int* __restrict__ DEG, int nrows) {
  __shared__ u32 cnt[256];
  __shared__ u32 offs[256];
  __shared__ u32 basearr[256];
  const int b = blockIdx.x, t = threadIdx.x;
  u32 count = cursor[b];
  if (count > BCAP) count = BCAP;
  cnt[t] = 0;
  __syncthreads();
  const u32* pb = pairs + (size_t)b * BCAP;
  for (u32 i = t * 4; i < count; i += 1024) {
    if (i + 3 < count) {
      uint4 v4 = *(const uint4*)(pb + i);
      atomicAdd(&cnt[v4.x & 255u], 1u);
      atomicAdd(&cnt[v4.y & 255u], 1u);
      atomicAdd(&cnt[v4.z & 255u], 1u);
      atomicAdd(&cnt[v4.w & 255u], 1u);
    } else {
      for (u32 k = 0; k < 4 && i + k < count; ++k) atomicAdd(&cnt[pb[i + k] & 255u], 1u);
    }
  }
  __syncthreads();
  const u32 my = cnt[t];
  offs[t] = my;
  __syncthreads();
  for (int d = 1; d < 256; d <<= 1) {
    u32 v = (t >= d) ? offs[t - d] : 0u;
    __syncthreads();
    offs[t] += v;
    __syncthreads();
  }
  const u32 excl = offs[t] - my;  // exclusive prefix
  const int node = (b << 8) + t;
  if (node < nrows) {
    RS[node] = b * BCAP + (int)excl;
    DEG[node] = (int)my;
  }
  basearr[t] = excl;
  cnt[t] = 0;
  __syncthreads();
#define SCAT(vv)                                          \
  {                                                       \
    u32 dl_ = (vv) & 255u;                                \
    u32 r_ = atomicAdd(&cnt[dl_], 1u);                    \
    csr[(size_t)b * BCAP + basearr[dl_] + r_] = (vv) >> 8; \
  }
  for (u32 i = t * 4; i < count; i += 1024) {
    if (i + 3 < count) {
      uint4 v4 = *(const uint4*)(pb + i);
      SCAT(v4.x)
      SCAT(v4.y)
      SCAT(v4.z)
      SCAT(v4.w)
    } else {
      for (u32 k = 0; k < 4 && i + k < count; ++k) SCAT(pb[i + k])
    }
  }
#undef SCAT
}

// ---- aggregation (EXACT r13/r15 inner loop — 69-70 us, its measured VALU/mem floor):
// AGG[i] = f(row(i)) + sum_j f(row(j)).  MODE 0: row(i)=TBL[x[i]], f=id.
// MODE 1: row(i)=H[i], f=BN-affine+relu (scsh precomputed). Fused per-edge BN (r9).
// SCALAR f32 math (pk asm regressed twice: r10, r14). 2-deep pipeline (r6).
// 32-bit byte offsets. FROZEN — do not touch.
template <int MODE>
__global__ __launch_bounds__(256) void agg_kernel(
    const u16* __restrict__ Hsrc, const int* __restrict__ x, const u32* __restrict__ csr,
    const int* __restrict__ RS, const int* __restrict__ DEG, const float* __restrict__ scsh,
    u16* __restrict__ AGG, int nrows) {
  int node = blockIdx.x * 4 + (threadIdx.x >> 6);
  if (node >= nrows) return;
  const int lane = threadIdx.x & 63;
  const int grp = lane >> 4;  // neighbor sub-slot 0..3
  const int fl = lane & 15;   // 16B feature chunk
  const int deg = DEG[node];
  const u32* cl = csr + RS[node];
  const char* Hb = (const char*)Hsrc;
  const u32 flo = (u32)fl << 4;

  float sc[8], sh[8];
  if (MODE == 1) {
#pragma unroll
    for (int i = 0; i < 8; ++i) {
      sc[i] = scsh[fl * 8 + i];
      sh[i] = scsh[128 + fl * 8 + i];
    }
  }
  float a[8];
#pragma unroll
  for (int i = 0; i < 8; ++i) a[i] = 0.f;

#define ACCUM(vv)                                   \
  {                                                 \
    const u16* p = (const u16*)&(vv);               \
    _Pragma("unroll") for (int i = 0; i < 8; ++i) { \
      float xv = bf2f(p[i]);                        \
      if (MODE == 1) {                              \
        xv = xv * sc[i] + sh[i];                    \
        xv = xv > 0.f ? xv : 0.f;                   \
      }                                             \
      a[i] += xv;                                   \
    }                                               \
  }
#define ROWOFF(idx) ((((u32)(MODE == 0 ? x[(idx)] : (idx))) << 8) + flo)

  if (grp == 0) {
    uint4 v = *(const uint4*)(Hb + ROWOFF(node));
    ACCUM(v);
  }
  int j = grp;
  int cA = (j < deg) ? (int)cl[j] : 0;
  int cB = (j + 4 < deg) ? (int)cl[j + 4] : 0;
  uint4 nv = make_uint4(0u, 0u, 0u, 0u);
  if (j < deg) nv = *(const uint4*)(Hb + ROWOFF(cA));
  while (j < deg) {
    uint4 cv = nv;
    int cn = cB;
    cB = (j + 8 < deg) ? (int)cl[j + 8] : 0;
    if (j + 4 < deg) nv = *(const uint4*)(Hb + ROWOFF(cn));
    ACCUM(cv);
    j += 4;
  }
#undef ROWOFF
#undef ACCUM

#pragma unroll
  for (int i = 0; i < 8; ++i) {
    a[i] += __shfl_xor(a[i], 16);
    a[i] += __shfl_xor(a[i], 32);
  }
  if (grp == 0) {
    u32 o[4];
#pragma unroll
    for (int i = 0; i < 4; ++i) o[i] = f2bf_pk(a[2 * i], a[2 * i + 1]);
    *(uint4*)(AGG + (size_t)node * 128 + fl * 8) = *(uint4*)o;
  }
}

// ---- fused 2-layer MLP (bf16 MFMA), 128-row x 128-col tile, 4 waves, T in-place,
// C routed through Xs then coalesced uint4 store (r13). HW cvt in epilogues (r14).
// BN stats -> PART plain stores (r12). EXACT r15 — frozen this round.
__global__ __launch_bounds__(256) void mlp_kernel(
    const u16* __restrict__ X, const u16* __restrict__ W1t, const float* __restrict__ b1,
    const u16* __restrict__ W2t, const float* __restrict__ b2, u16* __restrict__ Y,
    float* __restrict__ part, int nrows) {
  __shared__ u16 Xs[128 * 136];
  const int t = threadIdx.x;
  const int row0 = blockIdx.x * 128;
  {
    const int seg = t & 15;
    const int rb = t >> 4;
#pragma unroll
    for (int p = 0; p < 8; ++p) {
      const int r = rb + p * 16;
      const int gr = row0 + r;
      uint4 v = make_uint4(0u, 0u, 0u, 0u);
      if (gr < nrows) v = *(const uint4*)(X + (size_t)gr * 128 + seg * 8);
      *(uint4*)(Xs + r * 136 + seg * 8) = v;
    }
  }
  __syncthreads();
  const int lane = t & 63;
  const int wave = t >> 6;
  const int n0 = wave * 32;
  const int nl = lane & 15;
  const int quad = lane >> 4;

  bf16x8 bw[2][4];
#pragma unroll
  for (int nt = 0; nt < 2; ++nt)
#pragma unroll
    for (int kk = 0; kk < 4; ++kk)
      bw[nt][kk] = *(const bf16x8*)(W1t + (size_t)(n0 + nt * 16 + nl) * 128 + kk * 32 + quad * 8);

  f32x4 acc[8][2];
#pragma unroll
  for (int mt = 0; mt < 8; ++mt) {
    acc[mt][0] = (f32x4)0.0f;
    acc[mt][1] = (f32x4)0.0f;
  }
#pragma unroll
  for (int kk = 0; kk < 4; ++kk) {
#pragma unroll
    for (int mt = 0; mt < 8; ++mt) {
      bf16x8 a = *(const bf16x8*)(Xs + (mt * 16 + nl) * 136 + kk * 32 + quad * 8);
      acc[mt][0] = MFMA_BF16(a, bw[0][kk], acc[mt][0]);
      acc[mt][1] = MFMA_BF16(a, bw[1][kk], acc[mt][1]);
    }
  }
  __syncthreads();  // all GEMM1 A-reads complete before overwriting Xs with T
  // epilogue 1: bias + relu -> Xs (in place, bf16)
#pragma unroll
  for (int nt = 0; nt < 2; ++nt) {
    const int n = n0 + nt * 16 + nl;
    const float bias = b1[n];
#pragma unroll
    for (int mt = 0; mt < 8; ++mt)
#pragma unroll
      for (int r = 0; r < 4; ++r) {
        float v = acc[mt][nt][r] + bias;
        v = v > 0.f ? v : 0.f;
        Xs[(mt * 16 + quad * 4 + r) * 136 + n] = f2bf(v);
      }
  }
  __syncthreads();
  // GEMM2
#pragma unroll
  for (int nt = 0; nt < 2; ++nt)
#pragma unroll
    for (int kk = 0; kk < 4; ++kk)
      bw[nt][kk] = *(const bf16x8*)(W2t + (size_t)(n0 + nt * 16 + nl) * 128 + kk * 32 + quad * 8);
#pragma unroll
  for (int mt = 0; mt < 8; ++mt) {
    acc[mt][0] = (f32x4)0.0f;
    acc[mt][1] = (f32x4)0.0f;
  }
#pragma unroll
  for (int kk = 0; kk < 4; ++kk) {
#pragma unroll
    for (int mt = 0; mt < 8; ++mt) {
      bf16x8 a = *(const bf16x8*)(Xs + (mt * 16 + nl) * 136 + kk * 32 + quad * 8);
      acc[mt][0] = MFMA_BF16(a, bw[0][kk], acc[mt][0]);
      acc[mt][1] = MFMA_BF16(a, bw[1][kk], acc[mt][1]);
    }
  }
  __syncthreads();  // all GEMM2 A-reads complete before overwriting Xs with C
  // epilogue 2: bias; BN partials from registers; C -> Xs (bf16)
  float ssum[2] = {0.f, 0.f}, ssq[2] = {0.f, 0.f};
#pragma unroll
  for (int nt = 0; nt < 2; ++nt) {
    const int n = n0 + nt * 16 + nl;
    const float bias = b2[n];
#pragma unroll
    for (int mt = 0; mt < 8; ++mt)
#pragma unroll
      for (int r = 0; r < 4; ++r) {
        const int row = row0 + mt * 16 + quad * 4 + r;
        float v = acc[mt][nt][r] + bias;
        if (row < nrows) {
          ssum[nt] += v;
          ssq[nt] += v * v;
        }
        Xs[(mt * 16 + quad * 4 + r) * 136 + n] = f2bf(v);
      }
  }
#pragma unroll
  for (int nt = 0; nt < 2; ++nt) {
    float s = ssum[nt], q = ssq[nt];
    s += __shfl_xor(s, 16);
    q += __shfl_xor(q, 16);
    s += __shfl_xor(s, 32);
    q += __shfl_xor(q, 32);
    if (quad == 0) {
      const int n = n0 + nt * 16 + nl;
      part[(size_t)blockIdx.x * 256 + n] = s;
      part[(size_t)blockIdx.x * 256 + 128 + n] = q;
    }
  }
  __syncthreads();
  // coalesced Y store (same pattern as staging load)
  {
    const int seg = t & 15;
    const int rb = t >> 4;
#pragma unroll
    for (int p = 0; p < 8; ++p) {
      const int r = rb + p * 16;
      const int gr = row0 + r;
      if (gr < nrows)
        *(uint4*)(Y + (size_t)gr * 128 + seg * 8) = *(const uint4*)(Xs + r * 136 + seg * 8);
    }
  }
}

// ---- parallel column-reduce of PART + scale/shift compute (r12-proven, ~free)
__global__ __launch_bounds__(256) void bn_reduce_finalize(
    const float* __restrict__ part, int nblk, const float* __restrict__ g,
    const float* __restrict__ be, float invN, float* __restrict__ scsh) {
  __shared__ float red[2][128];
  const int c = blockIdx.x;  // 0..127
  const int t = threadIdx.x;
  const int half = t >> 7;
  const int tt = t & 127;
  const int col = c + half * 128;
  float s = 0.f;
  for (int b = tt; b < nblk; b += 128) s += part[(size_t)b * 256 + col];
  red[half][tt] = s;
  __syncthreads();
  for (int d = 64; d > 0; d >>= 1) {
    if (tt < d) red[half][tt] += red[half][tt + d];
    __syncthreads();
  }
  if (t == 0) {
    float mu = red[0][0] * invN;
    float var = red[1][0] * invN - mu * mu;
    float rstd = rsqrtf(var + 1e-5f);
    float sc = rstd * g[c];
    scsh[c] = sc;
    scsh[128 + c] = be[c] - mu * sc;
  }
}

// ---- pooling (fused layer-3 BN+relu via precomputed scsh) + final head, one block/graph
__global__ __launch_bounds__(256) void pool_final(
    const u16* __restrict__ Hh, const int* __restrict__ batch, const float* __restrict__ scsh,
    const float* __restrict__ f1w, const float* __restrict__ f1b, const float* __restrict__ f2w,
    const float* __restrict__ f2b, float* __restrict__ out, int nrows) {
  __shared__ float red[16][128];
  __shared__ float pr[128];
  __shared__ float tt[128];
  const int gid = blockIdx.x, t = threadIdx.x;
  int l = 0, r = nrows;
  while (l < r) {
    int m = (l + r) >> 1;
    if (batch[m] < gid) l = m + 1; else r = m;
  }
  const int s0 = l;
  r = nrows;
  while (l < r) {
    int m = (l + r) >> 1;
    if (batch[m] < gid + 1) l = m + 1; else r = m;
  }
  const int s1 = l;
  const int fl = t & 15;
  const int grp = t >> 4;
  float sc[8], sh[8];
#pragma unroll
  for (int i = 0; i < 8; ++i) {
    sc[i] = scsh[fl * 8 + i];
    sh[i] = scsh[128 + fl * 8 + i];
  }
  float a[8];
#pragma unroll
  for (int i = 0; i < 8; ++i) a[i] = 0.f;
  for (int i = s0 + grp; i < s1; i += 16) {
    uint4 v = *(const uint4*)(Hh + (size_t)i * 128 + fl * 8);
    const u16* pp = (const u16*)&v;
#pragma unroll
    for (int k = 0; k < 8; ++k) {
      float xv = bf2f(pp[k]) * sc[k] + sh[k];
      a[k] += xv > 0.f ? xv : 0.f;
    }
  }
#pragma unroll
  for (int k = 0; k < 8; ++k) red[grp][fl * 8 + k] = a[k];
  __syncthreads();
  if (t < 128) {
    float s = 0.f;
#pragma unroll
    for (int gg2 = 0; gg2 < 16; ++gg2) s += red[gg2][t];
    pr[t] = s;
  }
  __syncthreads();
  if (t < 128) {
    float s = f1b[t];
    for (int k = 0; k < 128; ++k) s += pr[k] * f1w[k * 128 + t];
    tt[t] = s > 0.f ? s : 0.f;
  }
  __syncthreads();
  if (t < 10) {
    float s2 = f2b[t];
    for (int k = 0; k < 128; ++k) s2 += tt[k] * f2w[k * 10 + t];
    out[gid * 10 + t] = s2;
  }
}

// ws layout (bytes):
//   H     @ 0          : 25,600,000  (bf16 node features)
//   AGG   @ 25,600,000 : 25,600,000  (bf16 aggregated, layer input tiles)
//   PAIRS @ 51,200,000 : 512*4608*4 = 9,437,184
//   CSR   @ 60,637,184 : 9,437,184
//   RS    @ 70,074,368 : 400,000
//   DEG   @ 70,474,368 : 400,000
//   CUR   @ 70,874,368 : 2,048       (zeroed)
//   SCSH  @ 70,876,416 : 3,072       (3 layers x 256 f32; written by bn_reduce_finalize)
//   WT    @ 70,879,488 : 196,608
//   TBL   @ 71,076,096 : 128,000
//   PART  @ 71,204,096 : 782*256*4 = 800,768 (per-block BN partials; fully overwritten)
extern "C" void kernel_launch(void* const* d_in, const int* in_sizes, int n_in, void* d_out,
                              int out_size, void* d_ws, size_t ws_size, hipStream_t stream) {
  const int* x = (const int*)d_in[0];
  const int* ei = (const int*)d_in[1];
  const int* batch = (const int*)d_in[2];
  const float* emb = (const float*)d_in[3];
  const float* iw1 = (const float*)d_in[4];
  const float* ib1 = (const float*)d_in[5];
  const float* iw2 = (const float*)d_in[6];
  const float* ib2 = (const float*)d_in[7];
  const float* f1w = (const float*)d_in[8];
  const float* f1b = (const float*)d_in[9];
  const float* f2w = (const float*)d_in[10];
  const float* f2b = (const float*)d_in[11];
  const float* cw1[3] = {(const float*)d_in[12], (const float*)d_in[18], (const float*)d_in[24]};
  const float* cb1[3] = {(const float*)d_in[13], (const float*)d_in[19], (const float*)d_in[25]};
  const float* cw2[3] = {(const float*)d_in[14], (const float*)d_in[20], (const float*)d_in[26]};
  const float* cb2[3] = {(const float*)d_in[15], (const float*)d_in[21], (const float*)d_in[27]};
  const float* gg[3] = {(const float*)d_in[16], (const float*)d_in[22], (const float*)d_in[28]};
  const float* bb[3] = {(const float*)d_in[17], (const float*)d_in[23], (const float*)d_in[29]};

  const int N_ = in_sizes[0];
  const int E_ = in_sizes[1] / 2;
  const int V_ = in_sizes[3] / 128;
  const int G_ = out_size / 10;
  const int NBUC = (N_ + 255) >> 8;
  const int NBUCKBLK = (E_ + EPB - 1) / EPB;
  const float invN = 1.0f / (float)N_;

  char* ws = (char*)d_ws;
  u16* H = (u16*)(ws + 0);
  u16* AGG = (u16*)(ws + 25600000);
  u32* PAIRS = (u32*)(ws + 51200000);
  u32* CSR = (u32*)(ws + 60637184);
  int* RS = (int*)(ws + 70074368);
  int* DEG = (int*)(ws + 70474368);
  u32* CUR = (u32*)(ws + 70874368);
  float* SCSH = (float*)(ws + 70876416);
  u16* WT = (u16*)(ws + 70879488);
  u16* TBL = (u16*)(ws + 71076096);
  float* PART = (float*)(ws + 71204096);

  hipMemsetAsync(ws + 70874368, 0, 2048, stream);  // CUR only

  setup_all<<<384 + V_ + NBUCKBLK, 256, 0, stream>>>(
      cw1[0], cw2[0], cw1[1], cw2[1], cw1[2], cw2[2], WT, emb, iw1, ib1, iw2, ib2, TBL, V_,
      ei, ei + E_, PAIRS, CUR, E_, NBUC);
  csr_build<<<NBUC, 256, 0, stream>>>(PAIRS, CUR, CSR, RS, DEG, N_);

  const int ablk = (N_ + 3) / 4;
  const int mblk = (N_ + 127) / 128;
  for (int l = 0; l < 3; ++l) {
    const u16* W1 = WT + (size_t)l * 32768;
    const u16* W2 = WT + (size_t)l * 32768 + 16384;
    if (l == 0)
      agg_kernel<0><<<ablk, 256, 0, stream>>>(TBL, x, CSR, RS, DEG, nullptr, AGG, N_);
    else
      agg_kernel<1><<<ablk, 256, 0, stream>>>(H, nullptr, CSR, RS, DEG, SCSH + (l - 1) * 256,
                                              AGG, N_);
    mlp_kernel<<<mblk, 256, 0, stream>>>(AGG, W1, cb1[l], W2, cb2[l], H, PART, N_);
    bn_reduce_finalize<<<128, 256, 0, stream>>>(PART, mblk, gg[l], bb[l], invN,
                                                SCSH + l * 256);
  }
  pool_final<<<G_, 256, 0, stream>>>(H, batch, SCSH + 2 * 256, f1w, f1b, f2w, f2b,
                                     (float*)d_out, N_);
}